// Round 1
// baseline (1843.101 us; speedup 1.0000x reference)
//
#include <hip/hip_runtime.h>
#include <hip/hip_bf16.h>
#include <math.h>

// Problem constants
#define BB 2
#define SS 1024
#define DD 1024
#define FF 4096
#define HH 16
#define EE 8
#define MM (BB*SS)          // 2048 tokens
#define HDIM (DD/HH)        // 64
#define MAX_TILES 40        // sum_e ceil(cnt_e/64) <= 2048/64 + 8

// ---------------- workspace layout (bytes) ----------------
#define OFF_QKV  ((size_t)0)                       // 2048*3072 f32 = 24MB (reused later as hid 2048*4096 = 32MB incl. attn slot)
#define OFF_ATTN ((size_t)25165824)                // 2048*1024 f32 = 8MB
#define OFF_H    ((size_t)33554432)                // 2048*1024 f32 (h1 then h2)
#define OFF_X2   ((size_t)41943040)                // 2048*1024 f32
#define OFF_GATE ((size_t)50331648)                // 2048 f32
#define OFF_EID  (OFF_GATE + 8192)                 // 2048 i32
#define OFF_PERM (OFF_EID + 8192)                  // 2048 i32
#define OFF_CNT  (OFF_PERM + 8192)                 // 8 i32   } zeroed
#define OFF_FILL (OFF_CNT + 32)                    // 8 i32   } zeroed
#define OFF_NT   (OFF_FILL + 32)                   // 1 i32   } zeroed (68 bytes total)
#define OFF_OFFS (OFF_NT + 4)                      // 9 i32
#define OFF_TE   (OFF_OFFS + 36)                   // 40 i32
#define OFF_TS   (OFF_TE + 160)                    // 40 i32
#define OFF_TR   (OFF_TS + 160)                    // 40 i32

// ---------------- LayerNorm (+optional RoPE) ----------------
template<bool ROPE>
__global__ void k_ln(const float* __restrict__ x, const float* __restrict__ w,
                     const float* __restrict__ b, float* __restrict__ out) {
    int m = blockIdx.x;            // token index (b*S + s)
    int s = m & (SS - 1);          // sequence position
    __shared__ float row[DD];
    __shared__ float red[8];
    int t = threadIdx.x;
    const float* xp = x + (size_t)m * DD;
    float sum = 0.f, sumsq = 0.f;
#pragma unroll
    for (int l = 0; l < 4; ++l) {
        int i = t + l * 256;
        float v = xp[i];
        row[i] = v;
        sum += v; sumsq += v * v;
    }
#pragma unroll
    for (int off = 32; off; off >>= 1) {
        sum   += __shfl_xor(sum, off);
        sumsq += __shfl_xor(sumsq, off);
    }
    int wid = t >> 6, lane = t & 63;
    if (lane == 0) { red[wid] = sum; red[4 + wid] = sumsq; }
    __syncthreads();
    sum   = red[0] + red[1] + red[2] + red[3];
    sumsq = red[4] + red[5] + red[6] + red[7];
    float mean = sum * (1.f / DD);
    float var  = sumsq * (1.f / DD) - mean * mean;
    float rstd = rsqrtf(var + 1e-5f);
    float* op = out + (size_t)m * DD;
    if (ROPE) {
        const float kln = logf(10000.f) / 512.f;
#pragma unroll
        for (int l = 0; l < 2; ++l) {
            int i = t + l * 256;   // 0..511
            float n1 = (row[i]       - mean) * rstd * w[i]       + b[i];
            float n2 = (row[i + 512] - mean) * rstd * w[i + 512] + b[i + 512];
            float inv = expf(-(float)i * kln);
            float ang = (float)s * inv;
            float c = cosf(ang), sn = sinf(ang);
            op[i]       = n1 * c - n2 * sn;
            op[i + 512] = n1 * sn + n2 * c;
        }
    } else {
#pragma unroll
        for (int l = 0; l < 4; ++l) {
            int i = t + l * 256;
            op[i] = (row[i] - mean) * rstd * w[i] + b[i];
        }
    }
}

// ---------------- generic fp32 GEMM: C = A @ Bt^T + bias (+add) ----------------
// A: MxK row-major, Bt: NxK row-major. M,N multiples of 64, K multiple of 16.
__global__ void k_gemm_bt(const float* __restrict__ A, const float* __restrict__ Bt,
                          const float* __restrict__ bias, const float* __restrict__ add,
                          float* __restrict__ C, int M, int N, int K) {
    __shared__ float As[16][65];
    __shared__ float Bs[16][65];
    int n0 = blockIdx.x * 64, m0 = blockIdx.y * 64;
    int t = threadIdx.x;
    int tx = t & 15, ty = t >> 4;
    float acc[4][4] = {};
    for (int k0 = 0; k0 < K; k0 += 16) {
#pragma unroll
        for (int l = 0; l < 4; ++l) {
            int idx = t + l * 256;
            int i = idx >> 4, kk = idx & 15;
            As[kk][i] = A[(size_t)(m0 + i) * K + k0 + kk];
            Bs[kk][i] = Bt[(size_t)(n0 + i) * K + k0 + kk];
        }
        __syncthreads();
#pragma unroll
        for (int kk = 0; kk < 16; ++kk) {
            float a[4], bv[4];
#pragma unroll
            for (int ii = 0; ii < 4; ++ii) a[ii]  = As[kk][ty * 4 + ii];
#pragma unroll
            for (int jj = 0; jj < 4; ++jj) bv[jj] = Bs[kk][tx * 4 + jj];
#pragma unroll
            for (int ii = 0; ii < 4; ++ii)
#pragma unroll
                for (int jj = 0; jj < 4; ++jj) acc[ii][jj] += a[ii] * bv[jj];
        }
        __syncthreads();
    }
#pragma unroll
    for (int ii = 0; ii < 4; ++ii) {
        int m = m0 + ty * 4 + ii;
#pragma unroll
        for (int jj = 0; jj < 4; ++jj) {
            int n = n0 + tx * 4 + jj;
            float v = acc[ii][jj] + bias[n];
            if (add) v += add[(size_t)m * N + n];
            C[(size_t)m * N + n] = v;
        }
    }
}

// ---------------- flash attention fp32 ----------------
// grid: (S/64, H, B), block 256. qkv: (M, 3072) with [q|k|v] each (H,64) per row.
__global__ void k_attn(const float* __restrict__ qkv, float* __restrict__ o) {
    int b = blockIdx.z, h = blockIdx.y, q0 = blockIdx.x * 64;
    __shared__ float Q[64][65], Kt[64][65], Vt[64][65], P[64][65];
    int t = threadIdx.x;
    int r = t >> 2, sub = t & 3;
    {   // load Q tile
        int i = t >> 2, c0 = (t & 3) * 16;
        const float* qp = qkv + (size_t)(b * SS + q0 + i) * 3072 + h * 64;
#pragma unroll
        for (int j = 0; j < 16; ++j) Q[i][c0 + j] = qp[c0 + j];
    }
    float mrun = -1e30f, lrun = 0.f;
    float oacc[16] = {};
    for (int k0 = 0; k0 < SS; k0 += 64) {
        __syncthreads();
        {   // load K,V tiles
            int i = t >> 2, c0 = (t & 3) * 16;
            const float* kp = qkv + (size_t)(b * SS + k0 + i) * 3072 + 1024 + h * 64;
            const float* vp = kp + 1024;
#pragma unroll
            for (int j = 0; j < 16; ++j) { Kt[i][c0 + j] = kp[c0 + j]; Vt[i][c0 + j] = vp[c0 + j]; }
        }
        __syncthreads();
        float sv[16];
#pragma unroll
        for (int j = 0; j < 16; ++j) {
            int c = sub * 16 + j;
            float acc = 0.f;
#pragma unroll
            for (int d = 0; d < 64; ++d) acc += Q[r][d] * Kt[c][d];
            sv[j] = acc * 0.125f;
        }
        float mx = sv[0];
#pragma unroll
        for (int j = 1; j < 16; ++j) mx = fmaxf(mx, sv[j]);
        mx = fmaxf(mx, __shfl_xor(mx, 1));
        mx = fmaxf(mx, __shfl_xor(mx, 2));
        float m_new = fmaxf(mrun, mx);
        float corr = expf(mrun - m_new);
        float psum = 0.f;
#pragma unroll
        for (int j = 0; j < 16; ++j) {
            float p = expf(sv[j] - m_new);
            psum += p;
            P[r][sub * 16 + j] = p;
        }
        psum += __shfl_xor(psum, 1);
        psum += __shfl_xor(psum, 2);
        lrun = lrun * corr + psum;
        mrun = m_new;
#pragma unroll
        for (int jj = 0; jj < 16; ++jj) oacc[jj] *= corr;
        __syncthreads();
        int d0 = sub * 16;
        for (int c = 0; c < 64; ++c) {
            float p = P[r][c];
#pragma unroll
            for (int jj = 0; jj < 16; ++jj) oacc[jj] += p * Vt[c][d0 + jj];
        }
    }
    float invl = 1.f / lrun;
    int d0 = sub * 16;
    float* op = o + (size_t)(b * SS + q0 + r) * DD + h * 64 + d0;
#pragma unroll
    for (int jj = 0; jj < 16; ++jj) op[jj] = oacc[jj] * invl;
}

// ---------------- router: logits, argmax gate, counts ----------------
__global__ void k_router(const float* __restrict__ h2, const float* __restrict__ wr,
                         float* __restrict__ logits_out, float* __restrict__ gate,
                         int* __restrict__ eid, int* __restrict__ counts) {
    int m = blockIdx.x;
    int lane = threadIdx.x;   // 64 threads
    const float* hp = h2 + (size_t)m * DD;
    float acc[EE] = {};
    for (int k = lane; k < DD; k += 64) {
        float v = hp[k];
        const float* wp = wr + (size_t)k * EE;
#pragma unroll
        for (int n = 0; n < EE; ++n) acc[n] += v * wp[n];
    }
#pragma unroll
    for (int off = 32; off; off >>= 1)
#pragma unroll
        for (int n = 0; n < EE; ++n) acc[n] += __shfl_xor(acc[n], off);
    if (lane == 0) {
        float mx = acc[0]; int best = 0;
#pragma unroll
        for (int n = 1; n < EE; ++n) if (acc[n] > mx) { mx = acc[n]; best = n; }
        float den = 0.f;
#pragma unroll
        for (int n = 0; n < EE; ++n) den += expf(acc[n] - mx);
        gate[m] = 1.f / den;            // softmax prob of the argmax expert
        eid[m] = best;
        atomicAdd(&counts[best], 1);
#pragma unroll
        for (int n = 0; n < EE; ++n) logits_out[(size_t)m * EE + n] = acc[n];
    }
}

// ---------------- routing bookkeeping ----------------
__global__ void k_offsets(const int* __restrict__ counts, int* __restrict__ offs,
                          int* __restrict__ te, int* __restrict__ ts, int* __restrict__ tr,
                          int* __restrict__ ntiles) {
    if (threadIdx.x != 0 || blockIdx.x != 0) return;
    int off = 0, nt = 0;
    for (int e = 0; e < EE; ++e) {
        offs[e] = off;
        int c = counts[e];
        for (int t0 = 0; t0 < c; t0 += 64) {
            te[nt] = e; ts[nt] = off + t0; tr[nt] = (c - t0 < 64) ? (c - t0) : 64; ++nt;
        }
        off += c;
    }
    offs[EE] = off;
    *ntiles = nt;
}

__global__ void k_scatter(const int* __restrict__ eid, const int* __restrict__ offs,
                          int* __restrict__ fill, int* __restrict__ perm) {
    int tok = blockIdx.x * 256 + threadIdx.x;
    if (tok >= MM) return;
    int e = eid[tok];
    int pos = offs[e] + atomicAdd(&fill[e], 1);
    perm[pos] = tok;
}

// ---------------- MoE grouped GEMM 1: hid = h2 @ wi[e]  (K=1024, N=4096) ----------------
__global__ void k_moe_gemm1(const float* __restrict__ h2, const float* __restrict__ wi,
                            const int* __restrict__ perm, const int* __restrict__ te,
                            const int* __restrict__ ts, const int* __restrict__ tr,
                            const int* __restrict__ ntiles, float* __restrict__ hid) {
    int tile = blockIdx.y;
    if (tile >= *ntiles) return;
    int e = te[tile], rs = ts[tile], rows = tr[tile];
    int n0 = blockIdx.x * 64;
    __shared__ float As[16][65];
    __shared__ float Bs[16][65];
    __shared__ int toks[64];
    int t = threadIdx.x;
    if (t < 64) toks[t] = (t < rows) ? perm[rs + t] : -1;
    __syncthreads();
    int tx = t & 15, ty = t >> 4;
    float acc[4][4] = {};
    const float* Bp = wi + (size_t)e * DD * FF;
    for (int k0 = 0; k0 < DD; k0 += 16) {
#pragma unroll
        for (int l = 0; l < 4; ++l) {
            int idx = t + l * 256;
            int i = idx >> 4, kk = idx & 15;
            int tok = toks[i];
            As[kk][i] = (tok >= 0) ? h2[(size_t)tok * DD + k0 + kk] : 0.f;
            int kk2 = idx >> 6, j = idx & 63;
            Bs[kk2][j] = Bp[(size_t)(k0 + kk2) * FF + n0 + j];
        }
        __syncthreads();
#pragma unroll
        for (int kk = 0; kk < 16; ++kk) {
            float a[4], bv[4];
#pragma unroll
            for (int ii = 0; ii < 4; ++ii) a[ii]  = As[kk][ty * 4 + ii];
#pragma unroll
            for (int jj = 0; jj < 4; ++jj) bv[jj] = Bs[kk][tx * 4 + jj];
#pragma unroll
            for (int ii = 0; ii < 4; ++ii)
#pragma unroll
                for (int jj = 0; jj < 4; ++jj) acc[ii][jj] += a[ii] * bv[jj];
        }
        __syncthreads();
    }
#pragma unroll
    for (int ii = 0; ii < 4; ++ii) {
        int tok = toks[ty * 4 + ii];
        if (tok < 0) continue;
#pragma unroll
        for (int jj = 0; jj < 4; ++jj)
            hid[(size_t)tok * FF + n0 + tx * 4 + jj] = acc[ii][jj];
    }
}

// ---------------- MoE grouped GEMM 2: out = x2 + gate * (silu(a)*g) @ wo[e] ----------------
__global__ void k_moe_gemm2(const float* __restrict__ hid, const float* __restrict__ wo,
                            const float* __restrict__ x2, const float* __restrict__ gate,
                            const int* __restrict__ perm, const int* __restrict__ te,
                            const int* __restrict__ ts, const int* __restrict__ tr,
                            const int* __restrict__ ntiles, float* __restrict__ out) {
    int tile = blockIdx.y;
    if (tile >= *ntiles) return;
    int e = te[tile], rs = ts[tile], rows = tr[tile];
    int n0 = blockIdx.x * 64;
    __shared__ float As[16][65];
    __shared__ float Bs[16][65];
    __shared__ int toks[64];
    int t = threadIdx.x;
    if (t < 64) toks[t] = (t < rows) ? perm[rs + t] : -1;
    __syncthreads();
    int tx = t & 15, ty = t >> 4;
    float acc[4][4] = {};
    const float* Bp = wo + (size_t)e * (FF / 2) * DD;
    for (int k0 = 0; k0 < FF / 2; k0 += 16) {
#pragma unroll
        for (int l = 0; l < 4; ++l) {
            int idx = t + l * 256;
            int i = idx >> 4, kk = idx & 15;
            int tok = toks[i];
            float av = 0.f;
            if (tok >= 0) {
                float a = hid[(size_t)tok * FF + k0 + kk];
                float g = hid[(size_t)tok * FF + 2048 + k0 + kk];
                av = (a / (1.f + expf(-a))) * g;   // silu(a) * g
            }
            As[kk][i] = av;
            int kk2 = idx >> 6, j = idx & 63;
            Bs[kk2][j] = Bp[(size_t)(k0 + kk2) * DD + n0 + j];
        }
        __syncthreads();
#pragma unroll
        for (int kk = 0; kk < 16; ++kk) {
            float a[4], bv[4];
#pragma unroll
            for (int ii = 0; ii < 4; ++ii) a[ii]  = As[kk][ty * 4 + ii];
#pragma unroll
            for (int jj = 0; jj < 4; ++jj) bv[jj] = Bs[kk][tx * 4 + jj];
#pragma unroll
            for (int ii = 0; ii < 4; ++ii)
#pragma unroll
                for (int jj = 0; jj < 4; ++jj) acc[ii][jj] += a[ii] * bv[jj];
        }
        __syncthreads();
    }
#pragma unroll
    for (int ii = 0; ii < 4; ++ii) {
        int tok = toks[ty * 4 + ii];
        if (tok < 0) continue;
        float gv = gate[tok];
#pragma unroll
        for (int jj = 0; jj < 4; ++jj) {
            int n = n0 + tx * 4 + jj;
            out[(size_t)tok * DD + n] = x2[(size_t)tok * DD + n] + gv * acc[ii][jj];
        }
    }
}

// ---------------- launch ----------------
extern "C" void kernel_launch(void* const* d_in, const int* in_sizes, int n_in,
                              void* d_out, int out_size, void* d_ws, size_t ws_size,
                              hipStream_t stream) {
    const float* x     = (const float*)d_in[0];
    const float* ln1w  = (const float*)d_in[1];
    const float* ln1b  = (const float*)d_in[2];
    const float* ln2w  = (const float*)d_in[3];
    const float* ln2b  = (const float*)d_in[4];
    const float* w_qkv = (const float*)d_in[5];
    const float* b_qkv = (const float*)d_in[6];
    const float* w_out = (const float*)d_in[7];
    const float* b_out = (const float*)d_in[8];
    const float* w_rtr = (const float*)d_in[9];
    const float* wi    = (const float*)d_in[10];
    const float* wo    = (const float*)d_in[11];
    float* out = (float*)d_out;

    char* wsb = (char*)d_ws;
    float* qkv  = (float*)(wsb + OFF_QKV);
    float* attn = (float*)(wsb + OFF_ATTN);
    float* hbuf = (float*)(wsb + OFF_H);
    float* x2   = (float*)(wsb + OFF_X2);
    float* hid  = (float*)(wsb + OFF_QKV);   // reuses qkv+attn space
    float* gate = (float*)(wsb + OFF_GATE);
    int* eid    = (int*)(wsb + OFF_EID);
    int* perm   = (int*)(wsb + OFF_PERM);
    int* counts = (int*)(wsb + OFF_CNT);
    int* fill   = (int*)(wsb + OFF_FILL);
    int* ntl    = (int*)(wsb + OFF_NT);
    int* offs   = (int*)(wsb + OFF_OFFS);
    int* te     = (int*)(wsb + OFF_TE);
    int* tsx    = (int*)(wsb + OFF_TS);
    int* trx    = (int*)(wsb + OFF_TR);

    // 1. LN1 + RoPE -> h1
    k_ln<true><<<MM, 256, 0, stream>>>(x, ln1w, ln1b, hbuf);
    // 2. qkv = h1 @ w_qkv^T + b_qkv
    k_gemm_bt<<<dim3(3072 / 64, MM / 64), 256, 0, stream>>>(hbuf, w_qkv, b_qkv, nullptr, qkv, MM, 3072, DD);
    // 3. attention
    k_attn<<<dim3(SS / 64, HH, BB), 256, 0, stream>>>(qkv, attn);
    // 4. x2 = x + attn @ w_out^T + b_out
    k_gemm_bt<<<dim3(DD / 64, MM / 64), 256, 0, stream>>>(attn, w_out, b_out, x, x2, MM, DD, DD);
    // 5. LN2 -> h2 (reuse hbuf)
    k_ln<false><<<MM, 256, 0, stream>>>(x2, ln2w, ln2b, hbuf);
    // 6. zero counts/fill/ntiles
    hipMemsetAsync(wsb + OFF_CNT, 0, 68, stream);
    // 7. router -> logits (second output region), gate, expert ids, counts
    k_router<<<MM, 64, 0, stream>>>(hbuf, w_rtr, out + (size_t)MM * DD, gate, eid, counts);
    // 8. offsets + tile descriptors
    k_offsets<<<1, 1, 0, stream>>>(counts, offs, te, tsx, trx, ntl);
    // 9. scatter tokens into per-expert buckets
    k_scatter<<<MM / 256, 256, 0, stream>>>(eid, offs, fill, perm);
    // 10. hid = h2 @ wi[e]
    k_moe_gemm1<<<dim3(FF / 64, MAX_TILES), 256, 0, stream>>>(hbuf, wi, perm, te, tsx, trx, ntl, hid);
    // 11. out = x2 + gate * (silu(a)*g) @ wo[e]
    k_moe_gemm2<<<dim3(DD / 64, MAX_TILES), 256, 0, stream>>>(hid, wo, x2, gate, perm, te, tsx, trx, ntl, out);
}

// Round 3
// 803.327 us; speedup vs baseline: 2.2943x; 2.2943x over previous
//
#include <hip/hip_runtime.h>
#include <hip/hip_bf16.h>
#include <math.h>

// Problem constants
#define BB 2
#define SS 1024
#define DD 1024
#define FF 4096
#define HH 16
#define EE 8
#define MM (BB*SS)          // 2048 tokens
#define MAX_TILES 24        // sum_e ceil(cnt_e/128) <= 2048/128 + 8

typedef __attribute__((ext_vector_type(8))) short bf16x8;
typedef __attribute__((ext_vector_type(4))) float f32x4;

// ---------------- workspace layout (bytes) ----------------
#define OFF_WIT  ((size_t)0)            // wi^T bf16: 8*4096*1024*2 = 67108864
#define OFF_WOT  ((size_t)67108864)     // wo^T bf16: 33554432
#define OFF_WQH  ((size_t)100663296)    // w_qkv hi bf16: 6291456
#define OFF_WQL  ((size_t)106954752)    // w_qkv lo bf16: 6291456
#define OFF_WOH  ((size_t)113246208)    // w_out hi bf16: 2097152
#define OFF_WOL  ((size_t)115343360)    // w_out lo bf16: 2097152
#define OFF_H1H  ((size_t)117440512)    // h1 hi bf16: 4194304
#define OFF_H1L  ((size_t)121634816)    // h1 lo bf16: 4194304
#define OFF_QKV  ((size_t)125829120)    // qkv f32: 25165824; later hid bf16 (16MB)
#define OFF_H2F  ((size_t)142606336)    // h2 f32: 8388608 (inside old qkv tail, free after attn)
#define OFF_OH   ((size_t)150994944)    // attn o hi bf16: 4194304
#define OFF_OL   ((size_t)155189248)    // attn o lo bf16: 4194304
#define OFF_X2   ((size_t)159383552)    // x2 f32: 8388608
#define OFF_H2B  ((size_t)167772160)    // h2 bf16: 4194304
#define OFF_ACT  ((size_t)171966464)    // act bf16 (2048+128)*2048*2 = 8912896
#define OFF_GATE ((size_t)180879360)
#define OFF_EID  ((size_t)180887552)
#define OFF_PERM ((size_t)180895744)
#define OFF_CNT  ((size_t)180903936)
#define OFF_FILL ((size_t)180903968)
#define OFF_NT   ((size_t)180904000)
#define OFF_OFFS ((size_t)180904064)
#define OFF_TE   ((size_t)180904192)
#define OFF_TS   ((size_t)180904320)
#define OFF_TR   ((size_t)180904448)

// ---------------- async global->LDS (16B per lane) ----------------
__device__ __forceinline__ void gload16(const void* g, void* l) {
    __builtin_amdgcn_global_load_lds(
        (const __attribute__((address_space(1))) unsigned int*)g,
        (__attribute__((address_space(3))) unsigned int*)l, 16, 0, 0);
}

__device__ __forceinline__ void split_write(float v, __hip_bfloat16* hp, __hip_bfloat16* lp, size_t idx) {
    __hip_bfloat16 h = __float2bfloat16(v);
    hp[idx] = h;
    lp[idx] = __float2bfloat16(v - __bfloat162float(h));
}

// ---------------- f32 -> bf16 hi/lo split convert ----------------
__global__ void k_cvt_split(const float* __restrict__ in, __hip_bfloat16* __restrict__ hi,
                            __hip_bfloat16* __restrict__ lo, int n4) {
    int i = blockIdx.x * 256 + threadIdx.x;
    if (i >= n4) return;
    float4 v = ((const float4*)in)[i];
    split_write(v.x, hi, lo, (size_t)i * 4 + 0);
    split_write(v.y, hi, lo, (size_t)i * 4 + 1);
    split_write(v.z, hi, lo, (size_t)i * 4 + 2);
    split_write(v.w, hi, lo, (size_t)i * 4 + 3);
}

// ---------------- batched transpose-convert: in (R,C) f32 -> out (C,R) bf16 ----------------
__global__ void k_tcvt(const float* __restrict__ in, __hip_bfloat16* __restrict__ out, int R, int C) {
    __shared__ float tile[32][33];
    int c0 = blockIdx.x * 32, r0 = blockIdx.y * 32;
    size_t eoff = (size_t)blockIdx.z * R * C;
    in += eoff; out += eoff;
    int t = threadIdx.x;
    int i = t >> 3, j0 = (t & 7) * 4;
    float4 v = *(const float4*)&in[(size_t)(r0 + i) * C + c0 + j0];
    tile[i][j0 + 0] = v.x; tile[i][j0 + 1] = v.y; tile[i][j0 + 2] = v.z; tile[i][j0 + 3] = v.w;
    __syncthreads();
#pragma unroll
    for (int q = 0; q < 4; ++q)
        out[(size_t)(c0 + i) * R + r0 + j0 + q] = __float2bfloat16(tile[j0 + q][i]);
}

// ---------------- LayerNorm: MODE 0 = +RoPE, hi/lo out; MODE 1 = plain, bf16+f32 out ----------------
template<int MODE>
__global__ void k_ln(const float* __restrict__ x, const float* __restrict__ w,
                     const float* __restrict__ b, __hip_bfloat16* __restrict__ hi,
                     __hip_bfloat16* __restrict__ lo, float* __restrict__ f32o) {
    int m = blockIdx.x;
    int s = m & (SS - 1);
    __shared__ float row[DD];
    __shared__ float red[8];
    int t = threadIdx.x;
    const float* xp = x + (size_t)m * DD;
    float sum = 0.f, sumsq = 0.f;
#pragma unroll
    for (int l = 0; l < 4; ++l) {
        int i = t + l * 256;
        float v = xp[i];
        row[i] = v;
        sum += v; sumsq += v * v;
    }
#pragma unroll
    for (int off = 32; off; off >>= 1) {
        sum   += __shfl_xor(sum, off);
        sumsq += __shfl_xor(sumsq, off);
    }
    int wid = t >> 6, lane = t & 63;
    if (lane == 0) { red[wid] = sum; red[4 + wid] = sumsq; }
    __syncthreads();
    sum   = red[0] + red[1] + red[2] + red[3];
    sumsq = red[4] + red[5] + red[6] + red[7];
    float mean = sum * (1.f / DD);
    float var  = sumsq * (1.f / DD) - mean * mean;
    float rstd = rsqrtf(var + 1e-5f);
    size_t base = (size_t)m * DD;
    if (MODE == 0) {
        const float kln = logf(10000.f) / 512.f;
#pragma unroll
        for (int l = 0; l < 2; ++l) {
            int i = t + l * 256;   // 0..511
            float n1 = (row[i]       - mean) * rstd * w[i]       + b[i];
            float n2 = (row[i + 512] - mean) * rstd * w[i + 512] + b[i + 512];
            float inv = expf(-(float)i * kln);
            float ang = (float)s * inv;
            float c = cosf(ang), sn = sinf(ang);
            split_write(n1 * c - n2 * sn,  hi, lo, base + i);
            split_write(n1 * sn + n2 * c, hi, lo, base + i + 512);
        }
    } else {
#pragma unroll
        for (int l = 0; l < 4; ++l) {
            int i = t + l * 256;
            float v = (row[i] - mean) * rstd * w[i] + b[i];
            hi[base + i] = __float2bfloat16(v);
            f32o[base + i] = v;
        }
    }
}

// ---------------- split-precision MFMA GEMM: C = A @ Bt^T + bias (+addsrc) ----------------
// A = Ah+Al, Bt = Bh+Bl (bf16 hi/lo pairs, M x K and N x K row-major).
// acc = Ah.Bh + Ah.Bl + Al.Bh  (~f32-grade). 128x128 tile, 4 waves, BK=32.
// MODE 0: Cf = acc + bias ; MODE 1: Cf = acc + bias + addsrc
template<int MODE>
__global__ void k_mfma_split(const __hip_bfloat16* __restrict__ Ah, const __hip_bfloat16* __restrict__ Al,
                             const __hip_bfloat16* __restrict__ Bh, const __hip_bfloat16* __restrict__ Bl,
                             const float* __restrict__ bias, const float* __restrict__ addsrc,
                             float* __restrict__ Cf, int M, int N, int K) {
    __shared__ __align__(16) short AsH[128 * 32];
    __shared__ __align__(16) short AsL[128 * 32];
    __shared__ __align__(16) short BsH[128 * 32];
    __shared__ __align__(16) short BsL[128 * 32];
    int m0 = blockIdx.y * 128, n0 = blockIdx.x * 128;
    const int t = threadIdx.x;
    const int w = t >> 6, lane = t & 63;
    const int wr = w >> 1, wc = w & 1;
    const int sid = w * 64 + lane;

    f32x4 acc[4][4] = {};

    for (int k0 = 0; k0 < K; k0 += 32) {
#pragma unroll
        for (int j = 0; j < 2; ++j) {
            int id = j * 256 + sid;
            int rrow = id >> 2, sl = id & 3;
            int slog = sl ^ ((rrow >> 1) & 3);
            size_t lbase = (size_t)(j * 256 + w * 64) * 8;
            size_t gaoff = (size_t)(m0 + rrow) * K + k0 + slog * 8;
            gload16(Ah + gaoff, &AsH[lbase]);
            gload16(Al + gaoff, &AsL[lbase]);
            size_t gboff = (size_t)(n0 + rrow) * K + k0 + slog * 8;
            gload16(Bh + gboff, &BsH[lbase]);
            gload16(Bl + gboff, &BsL[lbase]);
        }
        __syncthreads();
        bf16x8 ah[4], al[4], bh[4], bl[4];
#pragma unroll
        for (int i = 0; i < 4; ++i) {
            int ra = wr * 64 + i * 16 + (lane & 15);
            int pa = (lane >> 4) ^ ((ra >> 1) & 3);
            ah[i] = *(const bf16x8*)&AsH[ra * 32 + pa * 8];
            al[i] = *(const bf16x8*)&AsL[ra * 32 + pa * 8];
            int rb = wc * 64 + i * 16 + (lane & 15);
            int pb = (lane >> 4) ^ ((rb >> 1) & 3);
            bh[i] = *(const bf16x8*)&BsH[rb * 32 + pb * 8];
            bl[i] = *(const bf16x8*)&BsL[rb * 32 + pb * 8];
        }
#pragma unroll
        for (int i = 0; i < 4; ++i)
#pragma unroll
            for (int n = 0; n < 4; ++n) {
                acc[i][n] = __builtin_amdgcn_mfma_f32_16x16x32_bf16(ah[i], bh[n], acc[i][n], 0, 0, 0);
                acc[i][n] = __builtin_amdgcn_mfma_f32_16x16x32_bf16(ah[i], bl[n], acc[i][n], 0, 0, 0);
                acc[i][n] = __builtin_amdgcn_mfma_f32_16x16x32_bf16(al[i], bh[n], acc[i][n], 0, 0, 0);
            }
        __syncthreads();
    }

    int cn = n0 + wc * 64 + (lane & 15);
#pragma unroll
    for (int i = 0; i < 4; ++i) {
#pragma unroll
        for (int n = 0; n < 4; ++n) {
            int col = cn + n * 16;
#pragma unroll
            for (int q = 0; q < 4; ++q) {
                int r = wr * 64 + i * 16 + (lane >> 4) * 4 + q;
                float v = acc[i][n][q] + bias[col];
                if (MODE == 1) v += addsrc[(size_t)(m0 + r) * N + col];
                Cf[(size_t)(m0 + r) * N + col] = v;
            }
        }
    }
}

// ---------------- plain bf16 MFMA GEMM for MoE ----------------
// MODE 2: gather A rows via perm; Cb = bf16(acc)      (up-proj -> hid)
// MODE 3: A rows rs+r; out[tok] = addsrc[tok]+gate[tok]*acc (down-proj)
template<int MODE>
__global__ void k_mfma(const __hip_bfloat16* __restrict__ A,
                       const __hip_bfloat16* __restrict__ Bt,
                       const float* __restrict__ addsrc,
                       float* __restrict__ Cf,
                       __hip_bfloat16* __restrict__ Cb,
                       int N, int K,
                       const int* __restrict__ perm,
                       const int* __restrict__ te, const int* __restrict__ ts,
                       const int* __restrict__ tr, const int* __restrict__ ntl,
                       const float* __restrict__ gate) {
    __shared__ __align__(16) short As[128 * 32];
    __shared__ __align__(16) short Bs[128 * 32];
    __shared__ int permS[128];
    int tile = blockIdx.y;
    if (tile >= *ntl) return;
    int e = te[tile], rs = ts[tile], rows = tr[tile];
    if (threadIdx.x < 128) {
        int r = threadIdx.x;
        permS[r] = (r < rows) ? perm[rs + r] : 0;
    }
    __syncthreads();
    int n0 = blockIdx.x * 128;
    const int t = threadIdx.x;
    const int w = t >> 6, lane = t & 63;
    const int wr = w >> 1, wc = w & 1;
    const int sid = w * 64 + lane;

    const __hip_bfloat16* Bp = Bt + (size_t)e * (size_t)N * (size_t)K;

    f32x4 acc[4][4] = {};

    for (int k0 = 0; k0 < K; k0 += 32) {
#pragma unroll
        for (int j = 0; j < 2; ++j) {
            int id = j * 256 + sid;
            int rrow = id >> 2, sl = id & 3;
            int slog = sl ^ ((rrow >> 1) & 3);
            const __hip_bfloat16* ga;
            if (MODE == 2) ga = A + (size_t)permS[rrow] * K + k0 + slog * 8;
            else           ga = A + (size_t)(rs + rrow) * K + k0 + slog * 8;
            size_t lbase = (size_t)(j * 256 + w * 64) * 8;
            gload16(ga, &As[lbase]);
            gload16(Bp + (size_t)(n0 + rrow) * K + k0 + slog * 8, &Bs[lbase]);
        }
        __syncthreads();
        bf16x8 af[4], bfr[4];
#pragma unroll
        for (int i = 0; i < 4; ++i) {
            int ra = wr * 64 + i * 16 + (lane & 15);
            int pa = (lane >> 4) ^ ((ra >> 1) & 3);
            af[i] = *(const bf16x8*)&As[ra * 32 + pa * 8];
            int rb = wc * 64 + i * 16 + (lane & 15);
            int pb = (lane >> 4) ^ ((rb >> 1) & 3);
            bfr[i] = *(const bf16x8*)&Bs[rb * 32 + pb * 8];
        }
#pragma unroll
        for (int i = 0; i < 4; ++i)
#pragma unroll
            for (int n = 0; n < 4; ++n)
                acc[i][n] = __builtin_amdgcn_mfma_f32_16x16x32_bf16(af[i], bfr[n], acc[i][n], 0, 0, 0);
        __syncthreads();
    }

    int cn = n0 + wc * 64 + (lane & 15);
#pragma unroll
    for (int i = 0; i < 4; ++i) {
#pragma unroll
        for (int n = 0; n < 4; ++n) {
            int col = cn + n * 16;
#pragma unroll
            for (int q = 0; q < 4; ++q) {
                int r = wr * 64 + i * 16 + (lane >> 4) * 4 + q;
                if (r >= rows) continue;
                float v = acc[i][n][q];
                if (MODE == 2) {
                    Cb[(size_t)(rs + r) * N + col] = __float2bfloat16(v);
                } else {
                    int tok = permS[r];
                    Cf[(size_t)tok * N + col] = addsrc[(size_t)tok * N + col] + gate[tok] * v;
                }
            }
        }
    }
}

// ---------------- flash attention fp32 (f32 qkv in, hi/lo bf16 out) ----------------
__global__ void k_attn(const float* __restrict__ qkv, __hip_bfloat16* __restrict__ ohi,
                       __hip_bfloat16* __restrict__ olo) {
    int b = blockIdx.z, h = blockIdx.y, q0 = blockIdx.x * 64;
    __shared__ float Q[64][65], Kt[64][65], Vt[64][65], P[64][65];
    int t = threadIdx.x;
    int r = t >> 2, sub = t & 3;
    {
        int i = t >> 2, c0 = (t & 3) * 16;
        const float* qp = qkv + (size_t)(b * SS + q0 + i) * 3072 + h * 64;
#pragma unroll
        for (int j = 0; j < 16; ++j) Q[i][c0 + j] = qp[c0 + j];
    }
    float mrun = -1e30f, lrun = 0.f;
    float oacc[16] = {};
    for (int k0 = 0; k0 < SS; k0 += 64) {
        __syncthreads();
        {
            int i = t >> 2, c0 = (t & 3) * 16;
            const float* kp = qkv + (size_t)(b * SS + k0 + i) * 3072 + 1024 + h * 64;
            const float* vp = kp + 1024;
#pragma unroll
            for (int j = 0; j < 16; ++j) { Kt[i][c0 + j] = kp[c0 + j]; Vt[i][c0 + j] = vp[c0 + j]; }
        }
        __syncthreads();
        float sv[16];
#pragma unroll
        for (int j = 0; j < 16; ++j) {
            int c = sub * 16 + j;
            float acc = 0.f;
#pragma unroll
            for (int d = 0; d < 64; ++d) acc += Q[r][d] * Kt[c][d];
            sv[j] = acc * 0.125f;
        }
        float mx = sv[0];
#pragma unroll
        for (int j = 1; j < 16; ++j) mx = fmaxf(mx, sv[j]);
        mx = fmaxf(mx, __shfl_xor(mx, 1));
        mx = fmaxf(mx, __shfl_xor(mx, 2));
        float m_new = fmaxf(mrun, mx);
        float corr = expf(mrun - m_new);
        float psum = 0.f;
#pragma unroll
        for (int j = 0; j < 16; ++j) {
            float p = expf(sv[j] - m_new);
            psum += p;
            P[r][sub * 16 + j] = p;
        }
        psum += __shfl_xor(psum, 1);
        psum += __shfl_xor(psum, 2);
        lrun = lrun * corr + psum;
        mrun = m_new;
#pragma unroll
        for (int jj = 0; jj < 16; ++jj) oacc[jj] *= corr;
        __syncthreads();
        int d0 = sub * 16;
        for (int c = 0; c < 64; ++c) {
            float p = P[r][c];
#pragma unroll
            for (int jj = 0; jj < 16; ++jj) oacc[jj] += p * Vt[c][d0 + jj];
        }
    }
    float invl = 1.f / lrun;
    int d0 = sub * 16;
    size_t base = (size_t)(b * SS + q0 + r) * DD + h * 64 + d0;
#pragma unroll
    for (int jj = 0; jj < 16; ++jj) split_write(oacc[jj] * invl, ohi, olo, base + jj);
}

// ---------------- router (f32 h2 in) ----------------
__global__ void k_router(const float* __restrict__ h2, const float* __restrict__ wr,
                         float* __restrict__ logits_out, float* __restrict__ gate,
                         int* __restrict__ eid, int* __restrict__ counts) {
    int m = blockIdx.x;
    int lane = threadIdx.x;   // 64 threads
    const float* hp = h2 + (size_t)m * DD;
    float acc[EE] = {};
    for (int k = lane; k < DD; k += 64) {
        float v = hp[k];
        const float* wp = wr + (size_t)k * EE;
#pragma unroll
        for (int n = 0; n < EE; ++n) acc[n] += v * wp[n];
    }
#pragma unroll
    for (int off = 32; off; off >>= 1)
#pragma unroll
        for (int n = 0; n < EE; ++n) acc[n] += __shfl_xor(acc[n], off);
    if (lane == 0) {
        float mx = acc[0]; int best = 0;
#pragma unroll
        for (int n = 1; n < EE; ++n) if (acc[n] > mx) { mx = acc[n]; best = n; }
        float den = 0.f;
#pragma unroll
        for (int n = 0; n < EE; ++n) den += expf(acc[n] - mx);
        gate[m] = 1.f / den;
        eid[m] = best;
        atomicAdd(&counts[best], 1);
#pragma unroll
        for (int n = 0; n < EE; ++n) logits_out[(size_t)m * EE + n] = acc[n];
    }
}

// ---------------- routing bookkeeping (BM=128 tiles) ----------------
__global__ void k_offsets(const int* __restrict__ counts, int* __restrict__ offs,
                          int* __restrict__ te, int* __restrict__ ts, int* __restrict__ tr,
                          int* __restrict__ ntiles) {
    if (threadIdx.x != 0 || blockIdx.x != 0) return;
    int off = 0, nt = 0;
    for (int e = 0; e < EE; ++e) {
        offs[e] = off;
        int c = counts[e];
        for (int t0 = 0; t0 < c; t0 += 128) {
            te[nt] = e; ts[nt] = off + t0; tr[nt] = (c - t0 < 128) ? (c - t0) : 128; ++nt;
        }
        off += c;
    }
    offs[EE] = off;
    *ntiles = nt;
}

__global__ void k_scatter(const int* __restrict__ eid, const int* __restrict__ offs,
                          int* __restrict__ fill, int* __restrict__ perm) {
    int tok = blockIdx.x * 256 + threadIdx.x;
    if (tok >= MM) return;
    int e = eid[tok];
    int pos = offs[e] + atomicAdd(&fill[e], 1);
    perm[pos] = tok;
}

// ---------------- silu(a)*g: hid (p,4096) bf16 -> act (p,2048) bf16 ----------------
__global__ void k_act(const __hip_bfloat16* __restrict__ hid, __hip_bfloat16* __restrict__ act) {
    int idx = blockIdx.x * 256 + threadIdx.x;
    int p = idx >> 9, c4 = (idx & 511) * 4;
    const __hip_bfloat16* ap = hid + (size_t)p * FF + c4;
    const __hip_bfloat16* gp = ap + 2048;
    __hip_bfloat16* op = act + (size_t)p * 2048 + c4;
#pragma unroll
    for (int q = 0; q < 4; ++q) {
        float a = __bfloat162float(ap[q]);
        float g = __bfloat162float(gp[q]);
        op[q] = __float2bfloat16((a / (1.f + expf(-a))) * g);
    }
}

// ---------------- launch ----------------
extern "C" void kernel_launch(void* const* d_in, const int* in_sizes, int n_in,
                              void* d_out, int out_size, void* d_ws, size_t ws_size,
                              hipStream_t stream) {
    const float* x     = (const float*)d_in[0];
    const float* ln1w  = (const float*)d_in[1];
    const float* ln1b  = (const float*)d_in[2];
    const float* ln2w  = (const float*)d_in[3];
    const float* ln2b  = (const float*)d_in[4];
    const float* w_qkv = (const float*)d_in[5];
    const float* b_qkv = (const float*)d_in[6];
    const float* w_out = (const float*)d_in[7];
    const float* b_out = (const float*)d_in[8];
    const float* w_rtr = (const float*)d_in[9];
    const float* wi    = (const float*)d_in[10];
    const float* wo    = (const float*)d_in[11];
    float* out = (float*)d_out;

    char* wsb = (char*)d_ws;
    __hip_bfloat16* wiT  = (__hip_bfloat16*)(wsb + OFF_WIT);
    __hip_bfloat16* woT  = (__hip_bfloat16*)(wsb + OFF_WOT);
    __hip_bfloat16* wqH  = (__hip_bfloat16*)(wsb + OFF_WQH);
    __hip_bfloat16* wqL  = (__hip_bfloat16*)(wsb + OFF_WQL);
    __hip_bfloat16* woH  = (__hip_bfloat16*)(wsb + OFF_WOH);
    __hip_bfloat16* woL  = (__hip_bfloat16*)(wsb + OFF_WOL);
    __hip_bfloat16* h1H  = (__hip_bfloat16*)(wsb + OFF_H1H);
    __hip_bfloat16* h1L  = (__hip_bfloat16*)(wsb + OFF_H1L);
    float*          qkvF = (float*)(wsb + OFF_QKV);
    __hip_bfloat16* hidB = (__hip_bfloat16*)(wsb + OFF_QKV);   // reuse after attn
    float*          h2F  = (float*)(wsb + OFF_H2F);
    __hip_bfloat16* oH   = (__hip_bfloat16*)(wsb + OFF_OH);
    __hip_bfloat16* oL   = (__hip_bfloat16*)(wsb + OFF_OL);
    float*          x2F  = (float*)(wsb + OFF_X2);
    __hip_bfloat16* h2B  = (__hip_bfloat16*)(wsb + OFF_H2B);
    __hip_bfloat16* actB = (__hip_bfloat16*)(wsb + OFF_ACT);
    float* gate = (float*)(wsb + OFF_GATE);
    int* eid    = (int*)(wsb + OFF_EID);
    int* perm   = (int*)(wsb + OFF_PERM);
    int* counts = (int*)(wsb + OFF_CNT);
    int* fill   = (int*)(wsb + OFF_FILL);
    int* ntl    = (int*)(wsb + OFF_NT);
    int* offs   = (int*)(wsb + OFF_OFFS);
    int* te     = (int*)(wsb + OFF_TE);
    int* tsx    = (int*)(wsb + OFF_TS);
    int* trx    = (int*)(wsb + OFF_TR);

    // 0. weight conversion
    k_cvt_split<<<3072, 256, 0, stream>>>(w_qkv, wqH, wqL, 3072 * 1024 / 4);
    k_cvt_split<<<1024, 256, 0, stream>>>(w_out, woH, woL, 1024 * 1024 / 4);
    k_tcvt<<<dim3(4096 / 32, 1024 / 32, EE), 256, 0, stream>>>(wi, wiT, 1024, 4096);
    k_tcvt<<<dim3(1024 / 32, 2048 / 32, EE), 256, 0, stream>>>(wo, woT, 2048, 1024);

    // 1. LN1 + RoPE -> h1 hi/lo
    k_ln<0><<<MM, 256, 0, stream>>>(x, ln1w, ln1b, h1H, h1L, nullptr);
    // 2. qkv = h1 @ w_qkv^T + b_qkv (split precision, f32 out)
    k_mfma_split<0><<<dim3(3072 / 128, MM / 128), 256, 0, stream>>>(
        h1H, h1L, wqH, wqL, b_qkv, nullptr, qkvF, MM, 3072, DD);
    // 3. attention (f32 compute, hi/lo bf16 out)
    k_attn<<<dim3(SS / 64, HH, BB), 256, 0, stream>>>(qkvF, oH, oL);
    // 4. x2 = x + o @ w_out^T + b_out (split precision, f32)
    k_mfma_split<1><<<dim3(DD / 128, MM / 128), 256, 0, stream>>>(
        oH, oL, woH, woL, b_out, x, x2F, MM, DD, DD);
    // 5. LN2 -> h2 (bf16 + f32)
    k_ln<1><<<MM, 256, 0, stream>>>(x2F, ln2w, ln2b, h2B, nullptr, h2F);
    // 6. zero routing state
    hipMemsetAsync(wsb + OFF_CNT, 0, 68, stream);
    // 7. router (f32 h2 -> exact logits/argmax)
    k_router<<<MM, 64, 0, stream>>>(h2F, w_rtr, out + (size_t)MM * DD, gate, eid, counts);
    // 8-9. tiles + scatter
    k_offsets<<<1, 1, 0, stream>>>(counts, offs, te, tsx, trx, ntl);
    k_scatter<<<MM / 256, 256, 0, stream>>>(eid, offs, fill, perm);
    // 10. hid = h2[perm] @ wiT[e]^T (bf16 out)
    k_mfma<2><<<dim3(FF / 128, MAX_TILES), 256, 0, stream>>>(
        h2B, wiT, nullptr, nullptr, hidB, FF, DD,
        perm, te, tsx, trx, ntl, nullptr);
    // 11. act = silu(a)*g
    k_act<<<MM * 512 / 256, 256, 0, stream>>>(hidB, actB);
    // 12. out = x2 + gate * (act @ woT[e]^T)
    k_mfma<3><<<dim3(DD / 128, MAX_TILES), 256, 0, stream>>>(
        actB, woT, x2F, out, nullptr, DD, FF / 2,
        perm, te, tsx, trx, ntl, gate);
}

// Round 4
// 433.847 us; speedup vs baseline: 4.2483x; 1.8516x over previous
//
#include <hip/hip_runtime.h>
#include <hip/hip_bf16.h>
#include <math.h>

// Problem constants
#define BB 2
#define SS 1024
#define DD 1024
#define FF 4096
#define HH 16
#define EE 8
#define MM (BB*SS)          // 2048 tokens
#define MAX_TILES 24        // sum_e ceil(cnt_e/128) <= 2048/128 + 8

typedef __attribute__((ext_vector_type(8))) short bf16x8;
typedef __attribute__((ext_vector_type(4))) short s16x4;
typedef __attribute__((ext_vector_type(4))) float f32x4;

// ---------------- workspace layout (bytes) ----------------
#define OFF_WIT  ((size_t)0)            // wi^T bf16: 8*4096*1024*2 = 67108864
#define OFF_WOT  ((size_t)67108864)     // wo^T bf16: 33554432
#define OFF_WQH  ((size_t)100663296)    // w_qkv hi bf16: 6291456
#define OFF_WQL  ((size_t)106954752)    // w_qkv lo bf16: 6291456
#define OFF_WOH  ((size_t)113246208)    // w_out hi bf16: 2097152
#define OFF_WOL  ((size_t)115343360)    // w_out lo bf16: 2097152
#define OFF_H1H  ((size_t)117440512)    // h1 hi bf16: 4194304
#define OFF_H1L  ((size_t)121634816)    // h1 lo bf16: 4194304
#define OFF_QKV  ((size_t)125829120)    // qkv f32: 25165824; later hid bf16 (16MB)
#define OFF_H2F  ((size_t)142606336)    // h2 f32: 8388608
#define OFF_OH   ((size_t)150994944)    // attn o hi bf16: 4194304
#define OFF_OL   ((size_t)155189248)    // attn o lo bf16: 4194304
#define OFF_X2   ((size_t)159383552)    // x2 f32: 8388608
#define OFF_H2B  ((size_t)167772160)    // h2 bf16: 4194304
#define OFF_ACT  ((size_t)171966464)    // act bf16 (2048+128)*2048*2 = 8912896
#define OFF_GATE ((size_t)180879360)
#define OFF_EID  ((size_t)180887552)
#define OFF_PERM ((size_t)180895744)
#define OFF_CNT  ((size_t)180903936)
#define OFF_FILL ((size_t)180903968)
#define OFF_NT   ((size_t)180904000)
#define OFF_OFFS ((size_t)180904064)
#define OFF_TE   ((size_t)180904192)
#define OFF_TS   ((size_t)180904320)
#define OFF_TR   ((size_t)180904448)

// ---------------- async global->LDS (16B per lane) ----------------
__device__ __forceinline__ void gload16(const void* g, void* l) {
    __builtin_amdgcn_global_load_lds(
        (const __attribute__((address_space(1))) unsigned int*)g,
        (__attribute__((address_space(3))) unsigned int*)l, 16, 0, 0);
}

__device__ __forceinline__ short bfh(float v) {
    __hip_bfloat16 h = __float2bfloat16(v);
    return *(short*)&h;
}
__device__ __forceinline__ float bf2f(short s) {
    __hip_bfloat16 h = *(__hip_bfloat16*)&s;
    return __bfloat162float(h);
}

__device__ __forceinline__ void split_write(float v, __hip_bfloat16* hp, __hip_bfloat16* lp, size_t idx) {
    __hip_bfloat16 h = __float2bfloat16(v);
    hp[idx] = h;
    lp[idx] = __float2bfloat16(v - __bfloat162float(h));
}

// ---------------- f32 -> bf16 hi/lo split convert ----------------
__global__ void k_cvt_split(const float* __restrict__ in, __hip_bfloat16* __restrict__ hi,
                            __hip_bfloat16* __restrict__ lo, int n4) {
    int i = blockIdx.x * 256 + threadIdx.x;
    if (i >= n4) return;
    float4 v = ((const float4*)in)[i];
    split_write(v.x, hi, lo, (size_t)i * 4 + 0);
    split_write(v.y, hi, lo, (size_t)i * 4 + 1);
    split_write(v.z, hi, lo, (size_t)i * 4 + 2);
    split_write(v.w, hi, lo, (size_t)i * 4 + 3);
}

// ---------------- batched transpose-convert: in (R,C) f32 -> out (C,R) bf16 ----------------
__global__ void k_tcvt(const float* __restrict__ in, __hip_bfloat16* __restrict__ out, int R, int C) {
    __shared__ float tile[32][33];
    int c0 = blockIdx.x * 32, r0 = blockIdx.y * 32;
    size_t eoff = (size_t)blockIdx.z * R * C;
    in += eoff; out += eoff;
    int t = threadIdx.x;
    int i = t >> 3, j0 = (t & 7) * 4;
    float4 v = *(const float4*)&in[(size_t)(r0 + i) * C + c0 + j0];
    tile[i][j0 + 0] = v.x; tile[i][j0 + 1] = v.y; tile[i][j0 + 2] = v.z; tile[i][j0 + 3] = v.w;
    __syncthreads();
#pragma unroll
    for (int q = 0; q < 4; ++q)
        out[(size_t)(c0 + i) * R + r0 + j0 + q] = __float2bfloat16(tile[j0 + q][i]);
}

// ---------------- LayerNorm: MODE 0 = +RoPE, hi/lo out; MODE 1 = plain, bf16+f32 out ----------------
template<int MODE>
__global__ void k_ln(const float* __restrict__ x, const float* __restrict__ w,
                     const float* __restrict__ b, __hip_bfloat16* __restrict__ hi,
                     __hip_bfloat16* __restrict__ lo, float* __restrict__ f32o) {
    int m = blockIdx.x;
    int s = m & (SS - 1);
    __shared__ float row[DD];
    __shared__ float red[8];
    int t = threadIdx.x;
    const float* xp = x + (size_t)m * DD;
    float sum = 0.f, sumsq = 0.f;
#pragma unroll
    for (int l = 0; l < 4; ++l) {
        int i = t + l * 256;
        float v = xp[i];
        row[i] = v;
        sum += v; sumsq += v * v;
    }
#pragma unroll
    for (int off = 32; off; off >>= 1) {
        sum   += __shfl_xor(sum, off);
        sumsq += __shfl_xor(sumsq, off);
    }
    int wid = t >> 6, lane = t & 63;
    if (lane == 0) { red[wid] = sum; red[4 + wid] = sumsq; }
    __syncthreads();
    sum   = red[0] + red[1] + red[2] + red[3];
    sumsq = red[4] + red[5] + red[6] + red[7];
    float mean = sum * (1.f / DD);
    float var  = sumsq * (1.f / DD) - mean * mean;
    float rstd = rsqrtf(var + 1e-5f);
    size_t base = (size_t)m * DD;
    if (MODE == 0) {
        const float kln = logf(10000.f) / 512.f;
#pragma unroll
        for (int l = 0; l < 2; ++l) {
            int i = t + l * 256;   // 0..511
            float n1 = (row[i]       - mean) * rstd * w[i]       + b[i];
            float n2 = (row[i + 512] - mean) * rstd * w[i + 512] + b[i + 512];
            float inv = expf(-(float)i * kln);
            float ang = (float)s * inv;
            float c = cosf(ang), sn = sinf(ang);
            split_write(n1 * c - n2 * sn,  hi, lo, base + i);
            split_write(n1 * sn + n2 * c, hi, lo, base + i + 512);
        }
    } else {
#pragma unroll
        for (int l = 0; l < 4; ++l) {
            int i = t + l * 256;
            float v = (row[i] - mean) * rstd * w[i] + b[i];
            hi[base + i] = __float2bfloat16(v);
            f32o[base + i] = v;
        }
    }
}

// ---------------- split-precision MFMA GEMM: C = A @ Bt^T + bias (+addsrc) ----------------
template<int MODE>
__global__ void k_mfma_split(const __hip_bfloat16* __restrict__ Ah, const __hip_bfloat16* __restrict__ Al,
                             const __hip_bfloat16* __restrict__ Bh, const __hip_bfloat16* __restrict__ Bl,
                             const float* __restrict__ bias, const float* __restrict__ addsrc,
                             float* __restrict__ Cf, int M, int N, int K) {
    __shared__ __align__(16) short AsH[128 * 32];
    __shared__ __align__(16) short AsL[128 * 32];
    __shared__ __align__(16) short BsH[128 * 32];
    __shared__ __align__(16) short BsL[128 * 32];
    int m0 = blockIdx.y * 128, n0 = blockIdx.x * 128;
    const int t = threadIdx.x;
    const int w = t >> 6, lane = t & 63;
    const int wr = w >> 1, wc = w & 1;
    const int sid = w * 64 + lane;

    f32x4 acc[4][4] = {};

    for (int k0 = 0; k0 < K; k0 += 32) {
#pragma unroll
        for (int j = 0; j < 2; ++j) {
            int id = j * 256 + sid;
            int rrow = id >> 2, sl = id & 3;
            int slog = sl ^ ((rrow >> 1) & 3);
            size_t lbase = (size_t)(j * 256 + w * 64) * 8;
            size_t gaoff = (size_t)(m0 + rrow) * K + k0 + slog * 8;
            gload16(Ah + gaoff, &AsH[lbase]);
            gload16(Al + gaoff, &AsL[lbase]);
            size_t gboff = (size_t)(n0 + rrow) * K + k0 + slog * 8;
            gload16(Bh + gboff, &BsH[lbase]);
            gload16(Bl + gboff, &BsL[lbase]);
        }
        __syncthreads();
        bf16x8 ah[4], al[4], bh[4], bl[4];
#pragma unroll
        for (int i = 0; i < 4; ++i) {
            int ra = wr * 64 + i * 16 + (lane & 15);
            int pa = (lane >> 4) ^ ((ra >> 1) & 3);
            ah[i] = *(const bf16x8*)&AsH[ra * 32 + pa * 8];
            al[i] = *(const bf16x8*)&AsL[ra * 32 + pa * 8];
            int rb = wc * 64 + i * 16 + (lane & 15);
            int pb = (lane >> 4) ^ ((rb >> 1) & 3);
            bh[i] = *(const bf16x8*)&BsH[rb * 32 + pb * 8];
            bl[i] = *(const bf16x8*)&BsL[rb * 32 + pb * 8];
        }
#pragma unroll
        for (int i = 0; i < 4; ++i)
#pragma unroll
            for (int n = 0; n < 4; ++n) {
                acc[i][n] = __builtin_amdgcn_mfma_f32_16x16x32_bf16(ah[i], bh[n], acc[i][n], 0, 0, 0);
                acc[i][n] = __builtin_amdgcn_mfma_f32_16x16x32_bf16(ah[i], bl[n], acc[i][n], 0, 0, 0);
                acc[i][n] = __builtin_amdgcn_mfma_f32_16x16x32_bf16(al[i], bh[n], acc[i][n], 0, 0, 0);
            }
        __syncthreads();
    }

    int cn = n0 + wc * 64 + (lane & 15);
#pragma unroll
    for (int i = 0; i < 4; ++i) {
#pragma unroll
        for (int n = 0; n < 4; ++n) {
            int col = cn + n * 16;
#pragma unroll
            for (int q = 0; q < 4; ++q) {
                int r = wr * 64 + i * 16 + (lane >> 4) * 4 + q;
                float v = acc[i][n][q] + bias[col];
                if (MODE == 1) v += addsrc[(size_t)(m0 + r) * N + col];
                Cf[(size_t)(m0 + r) * N + col] = v;
            }
        }
    }
}

// ---------------- plain bf16 MFMA GEMM for MoE ----------------
template<int MODE>
__global__ void k_mfma(const __hip_bfloat16* __restrict__ A,
                       const __hip_bfloat16* __restrict__ Bt,
                       const float* __restrict__ addsrc,
                       float* __restrict__ Cf,
                       __hip_bfloat16* __restrict__ Cb,
                       int N, int K,
                       const int* __restrict__ perm,
                       const int* __restrict__ te, const int* __restrict__ ts,
                       const int* __restrict__ tr, const int* __restrict__ ntl,
                       const float* __restrict__ gate) {
    __shared__ __align__(16) short As[128 * 32];
    __shared__ __align__(16) short Bs[128 * 32];
    __shared__ int permS[128];
    int tile = blockIdx.y;
    if (tile >= *ntl) return;
    int e = te[tile], rs = ts[tile], rows = tr[tile];
    if (threadIdx.x < 128) {
        int r = threadIdx.x;
        permS[r] = (r < rows) ? perm[rs + r] : 0;
    }
    __syncthreads();
    int n0 = blockIdx.x * 128;
    const int t = threadIdx.x;
    const int w = t >> 6, lane = t & 63;
    const int wr = w >> 1, wc = w & 1;
    const int sid = w * 64 + lane;

    const __hip_bfloat16* Bp = Bt + (size_t)e * (size_t)N * (size_t)K;

    f32x4 acc[4][4] = {};

    for (int k0 = 0; k0 < K; k0 += 32) {
#pragma unroll
        for (int j = 0; j < 2; ++j) {
            int id = j * 256 + sid;
            int rrow = id >> 2, sl = id & 3;
            int slog = sl ^ ((rrow >> 1) & 3);
            const __hip_bfloat16* ga;
            if (MODE == 2) ga = A + (size_t)permS[rrow] * K + k0 + slog * 8;
            else           ga = A + (size_t)(rs + rrow) * K + k0 + slog * 8;
            size_t lbase = (size_t)(j * 256 + w * 64) * 8;
            gload16(ga, &As[lbase]);
            gload16(Bp + (size_t)(n0 + rrow) * K + k0 + slog * 8, &Bs[lbase]);
        }
        __syncthreads();
        bf16x8 af[4], bfr[4];
#pragma unroll
        for (int i = 0; i < 4; ++i) {
            int ra = wr * 64 + i * 16 + (lane & 15);
            int pa = (lane >> 4) ^ ((ra >> 1) & 3);
            af[i] = *(const bf16x8*)&As[ra * 32 + pa * 8];
            int rb = wc * 64 + i * 16 + (lane & 15);
            int pb = (lane >> 4) ^ ((rb >> 1) & 3);
            bfr[i] = *(const bf16x8*)&Bs[rb * 32 + pb * 8];
        }
#pragma unroll
        for (int i = 0; i < 4; ++i)
#pragma unroll
            for (int n = 0; n < 4; ++n)
                acc[i][n] = __builtin_amdgcn_mfma_f32_16x16x32_bf16(af[i], bfr[n], acc[i][n], 0, 0, 0);
        __syncthreads();
    }

    int cn = n0 + wc * 64 + (lane & 15);
#pragma unroll
    for (int i = 0; i < 4; ++i) {
#pragma unroll
        for (int n = 0; n < 4; ++n) {
            int col = cn + n * 16;
#pragma unroll
            for (int q = 0; q < 4; ++q) {
                int r = wr * 64 + i * 16 + (lane >> 4) * 4 + q;
                if (r >= rows) continue;
                float v = acc[i][n][q];
                if (MODE == 2) {
                    Cb[(size_t)(rs + r) * N + col] = __float2bfloat16(v);
                } else {
                    int tok = permS[r];
                    Cf[(size_t)tok * N + col] = addsrc[(size_t)tok * N + col] + gate[tok] * v;
                }
            }
        }
    }
}

// ---------------- MFMA flash attention, split-precision (f32-grade) ----------------
// One (b,h), 128 q-rows per block; 4 waves x 32 q-rows. K/V tiles of 64.
// S = Qh.Kh + Qh.Kl + Ql.Kh ; O = Ph.Vh + Ph.Vl + Pl.Vh. Q prescaled by 1/8.
#define QB 128
#define KB 64
#define LDK 72   // row stride (bf16) for Q/K/P tiles
#define LDV 72   // row stride for transposed V tiles
__global__ __launch_bounds__(256, 1)
void k_attn_mfma(const float* __restrict__ qkv,
                 __hip_bfloat16* __restrict__ ohi, __hip_bfloat16* __restrict__ olo) {
    __shared__ __align__(16) short Qh[QB * LDK], Ql[QB * LDK];
    __shared__ __align__(16) short Kh[KB * LDK], Kl[KB * LDK];
    __shared__ __align__(16) short Vh[64 * LDV], Vl[64 * LDV];   // [d][k] transposed
    __shared__ __align__(16) short Ph[4][32 * LDK], Pl[4][32 * LDK];
    int b = blockIdx.z, h = blockIdx.y, q0 = blockIdx.x * QB;
    int t = threadIdx.x;
    int w = t >> 6, lane = t & 63;
    int g = lane >> 4, r16 = lane & 15;

    // ---- stage Q (once), prescaled by 0.125
    {
        int qr = t >> 1, c0 = (t & 1) * 32;
        const float* qp = qkv + (size_t)(b * SS + q0 + qr) * 3072 + h * 64 + c0;
#pragma unroll
        for (int j4 = 0; j4 < 32; j4 += 4) {
            float4 v = *(const float4*)(qp + j4);
            v.x *= 0.125f; v.y *= 0.125f; v.z *= 0.125f; v.w *= 0.125f;
            s16x4 hv, lv;
            hv[0] = bfh(v.x); lv[0] = bfh(v.x - bf2f(hv[0]));
            hv[1] = bfh(v.y); lv[1] = bfh(v.y - bf2f(hv[1]));
            hv[2] = bfh(v.z); lv[2] = bfh(v.z - bf2f(hv[2]));
            hv[3] = bfh(v.w); lv[3] = bfh(v.w - bf2f(hv[3]));
            *(s16x4*)&Qh[qr * LDK + c0 + j4] = hv;
            *(s16x4*)&Ql[qr * LDK + c0 + j4] = lv;
        }
    }
    __syncthreads();

    // ---- hoist Q fragments (A-operand): rows w*32 + i*16 + r16
    bf16x8 qfh[2][2], qfl[2][2];
#pragma unroll
    for (int i = 0; i < 2; ++i)
#pragma unroll
        for (int ks = 0; ks < 2; ++ks) {
            int row = w * 32 + i * 16 + r16;
            qfh[i][ks] = *(const bf16x8*)&Qh[row * LDK + ks * 32 + g * 8];
            qfl[i][ks] = *(const bf16x8*)&Ql[row * LDK + ks * 32 + g * 8];
        }

    float mrun[2][4], lrun[2][4];
    f32x4 oacc[2][4] = {};
#pragma unroll
    for (int i = 0; i < 2; ++i)
#pragma unroll
        for (int q = 0; q < 4; ++q) { mrun[i][q] = -1e30f; lrun[i][q] = 0.f; }

    for (int k0 = 0; k0 < SS; k0 += KB) {
        // ---- stage K (row-major) and V (transposed, XOR-swizzled)
        {
            int kr = t >> 2, c0 = (t & 3) * 16;
            const float* kp = qkv + (size_t)(b * SS + k0 + kr) * 3072 + 1024 + h * 64 + c0;
            const float* vp = kp + 1024;
#pragma unroll
            for (int j4 = 0; j4 < 16; j4 += 4) {
                float4 kv = *(const float4*)(kp + j4);
                s16x4 khv, klv;
                khv[0] = bfh(kv.x); klv[0] = bfh(kv.x - bf2f(khv[0]));
                khv[1] = bfh(kv.y); klv[1] = bfh(kv.y - bf2f(khv[1]));
                khv[2] = bfh(kv.z); klv[2] = bfh(kv.z - bf2f(khv[2]));
                khv[3] = bfh(kv.w); klv[3] = bfh(kv.w - bf2f(khv[3]));
                *(s16x4*)&Kh[kr * LDK + c0 + j4] = khv;
                *(s16x4*)&Kl[kr * LDK + c0 + j4] = klv;
                float4 vv = *(const float4*)(vp + j4);
                float vs[4] = { vv.x, vv.y, vv.z, vv.w };
#pragma unroll
                for (int q = 0; q < 4; ++q) {
                    int d = c0 + j4 + q;
                    int swz = (d & 7) ^ ((d >> 3) & 7);
                    int pc = (((kr >> 3) ^ swz) << 3) | (kr & 7);
                    short vh_ = bfh(vs[q]);
                    Vh[d * LDV + pc] = vh_;
                    Vl[d * LDV + pc] = bfh(vs[q] - bf2f(vh_));
                }
            }
        }
        __syncthreads();

        // ---- S = Q K^T (split, 3 MFMA per fragment)
        f32x4 accs[2][4] = {};
#pragma unroll
        for (int ks = 0; ks < 2; ++ks) {
            bf16x8 kfh[4], kfl[4];
#pragma unroll
            for (int n = 0; n < 4; ++n) {
                int rb = n * 16 + r16;
                kfh[n] = *(const bf16x8*)&Kh[rb * LDK + ks * 32 + g * 8];
                kfl[n] = *(const bf16x8*)&Kl[rb * LDK + ks * 32 + g * 8];
            }
#pragma unroll
            for (int i = 0; i < 2; ++i)
#pragma unroll
                for (int n = 0; n < 4; ++n) {
                    accs[i][n] = __builtin_amdgcn_mfma_f32_16x16x32_bf16(qfh[i][ks], kfh[n], accs[i][n], 0, 0, 0);
                    accs[i][n] = __builtin_amdgcn_mfma_f32_16x16x32_bf16(qfh[i][ks], kfl[n], accs[i][n], 0, 0, 0);
                    accs[i][n] = __builtin_amdgcn_mfma_f32_16x16x32_bf16(qfl[i][ks], kfh[n], accs[i][n], 0, 0, 0);
                }
        }

        // ---- online softmax (per q-row; rows live in reg q across 16-lane groups)
#pragma unroll
        for (int i = 0; i < 2; ++i) {
            float mn[4], corr[4], psum[4];
#pragma unroll
            for (int q = 0; q < 4; ++q) {
                float m = fmaxf(fmaxf(accs[i][0][q], accs[i][1][q]),
                                fmaxf(accs[i][2][q], accs[i][3][q]));
                m = fmaxf(m, __shfl_xor(m, 1));
                m = fmaxf(m, __shfl_xor(m, 2));
                m = fmaxf(m, __shfl_xor(m, 4));
                m = fmaxf(m, __shfl_xor(m, 8));
                mn[q] = fmaxf(mrun[i][q], m);
                corr[q] = expf(mrun[i][q] - mn[q]);
                mrun[i][q] = mn[q];
                psum[q] = 0.f;
            }
#pragma unroll
            for (int n = 0; n < 4; ++n)
#pragma unroll
                for (int q = 0; q < 4; ++q) {
                    float p = expf(accs[i][n][q] - mn[q]);
                    psum[q] += p;
                    int row = i * 16 + g * 4 + q;
                    short ph_ = bfh(p);
                    Ph[w][row * LDK + n * 16 + r16] = ph_;
                    Pl[w][row * LDK + n * 16 + r16] = bfh(p - bf2f(ph_));
                }
#pragma unroll
            for (int q = 0; q < 4; ++q) {
                psum[q] += __shfl_xor(psum[q], 1);
                psum[q] += __shfl_xor(psum[q], 2);
                psum[q] += __shfl_xor(psum[q], 4);
                psum[q] += __shfl_xor(psum[q], 8);
                lrun[i][q] = lrun[i][q] * corr[q] + psum[q];
#pragma unroll
                for (int n = 0; n < 4; ++n) oacc[i][n][q] *= corr[q];
            }
        }

        // ---- O += P V (split). P from own wave's LDS region; V transposed.
#pragma unroll
        for (int ks = 0; ks < 2; ++ks) {
            bf16x8 vfh[4], vfl[4];
#pragma unroll
            for (int n = 0; n < 4; ++n) {
                int d = n * 16 + r16;
                int swz = (d & 7) ^ ((d >> 3) & 7);
                int blk = (ks * 4 + g) ^ swz;
                vfh[n] = *(const bf16x8*)&Vh[d * LDV + blk * 8];
                vfl[n] = *(const bf16x8*)&Vl[d * LDV + blk * 8];
            }
#pragma unroll
            for (int i = 0; i < 2; ++i) {
                bf16x8 pfh = *(const bf16x8*)&Ph[w][(i * 16 + r16) * LDK + ks * 32 + g * 8];
                bf16x8 pfl = *(const bf16x8*)&Pl[w][(i * 16 + r16) * LDK + ks * 32 + g * 8];
#pragma unroll
                for (int n = 0; n < 4; ++n) {
                    oacc[i][n] = __builtin_amdgcn_mfma_f32_16x16x32_bf16(pfh, vfh[n], oacc[i][n], 0, 0, 0);
                    oacc[i][n] = __builtin_amdgcn_mfma_f32_16x16x32_bf16(pfh, vfl[n], oacc[i][n], 0, 0, 0);
                    oacc[i][n] = __builtin_amdgcn_mfma_f32_16x16x32_bf16(pfl, vfh[n], oacc[i][n], 0, 0, 0);
                }
            }
        }
        __syncthreads();
    }

    // ---- epilogue: O / l, split hi/lo write
#pragma unroll
    for (int i = 0; i < 2; ++i) {
        float invl[4];
#pragma unroll
        for (int q = 0; q < 4; ++q) invl[q] = 1.f / lrun[i][q];
#pragma unroll
        for (int n = 0; n < 4; ++n) {
            int col = h * 64 + n * 16 + r16;
#pragma unroll
            for (int q = 0; q < 4; ++q) {
                int rowg = b * SS + q0 + w * 32 + i * 16 + g * 4 + q;
                split_write(oacc[i][n][q] * invl[q], ohi, olo, (size_t)rowg * DD + col);
            }
        }
    }
}

// ---------------- router (f32 h2 in) ----------------
__global__ void k_router(const float* __restrict__ h2, const float* __restrict__ wr,
                         float* __restrict__ logits_out, float* __restrict__ gate,
                         int* __restrict__ eid, int* __restrict__ counts) {
    int m = blockIdx.x;
    int lane = threadIdx.x;   // 64 threads
    const float* hp = h2 + (size_t)m * DD;
    float acc[EE] = {};
    for (int k = lane; k < DD; k += 64) {
        float v = hp[k];
        const float* wp = wr + (size_t)k * EE;
#pragma unroll
        for (int n = 0; n < EE; ++n) acc[n] += v * wp[n];
    }
#pragma unroll
    for (int off = 32; off; off >>= 1)
#pragma unroll
        for (int n = 0; n < EE; ++n) acc[n] += __shfl_xor(acc[n], off);
    if (lane == 0) {
        float mx = acc[0]; int best = 0;
#pragma unroll
        for (int n = 1; n < EE; ++n) if (acc[n] > mx) { mx = acc[n]; best = n; }
        float den = 0.f;
#pragma unroll
        for (int n = 0; n < EE; ++n) den += expf(acc[n] - mx);
        gate[m] = 1.f / den;
        eid[m] = best;
        atomicAdd(&counts[best], 1);
#pragma unroll
        for (int n = 0; n < EE; ++n) logits_out[(size_t)m * EE + n] = acc[n];
    }
}

// ---------------- routing bookkeeping (BM=128 tiles) ----------------
__global__ void k_offsets(const int* __restrict__ counts, int* __restrict__ offs,
                          int* __restrict__ te, int* __restrict__ ts, int* __restrict__ tr,
                          int* __restrict__ ntiles) {
    if (threadIdx.x != 0 || blockIdx.x != 0) return;
    int off = 0, nt = 0;
    for (int e = 0; e < EE; ++e) {
        offs[e] = off;
        int c = counts[e];
        for (int t0 = 0; t0 < c; t0 += 128) {
            te[nt] = e; ts[nt] = off + t0; tr[nt] = (c - t0 < 128) ? (c - t0) : 128; ++nt;
        }
        off += c;
    }
    offs[EE] = off;
    *ntiles = nt;
}

__global__ void k_scatter(const int* __restrict__ eid, const int* __restrict__ offs,
                          int* __restrict__ fill, int* __restrict__ perm) {
    int tok = blockIdx.x * 256 + threadIdx.x;
    if (tok >= MM) return;
    int e = eid[tok];
    int pos = offs[e] + atomicAdd(&fill[e], 1);
    perm[pos] = tok;
}

// ---------------- silu(a)*g: hid (p,4096) bf16 -> act (p,2048) bf16 ----------------
__global__ void k_act(const __hip_bfloat16* __restrict__ hid, __hip_bfloat16* __restrict__ act) {
    int idx = blockIdx.x * 256 + threadIdx.x;
    int p = idx >> 9, c4 = (idx & 511) * 4;
    const __hip_bfloat16* ap = hid + (size_t)p * FF + c4;
    const __hip_bfloat16* gp = ap + 2048;
    __hip_bfloat16* op = act + (size_t)p * 2048 + c4;
#pragma unroll
    for (int q = 0; q < 4; ++q) {
        float a = __bfloat162float(ap[q]);
        float g = __bfloat162float(gp[q]);
        op[q] = __float2bfloat16((a / (1.f + expf(-a))) * g);
    }
}

// ---------------- launch ----------------
extern "C" void kernel_launch(void* const* d_in, const int* in_sizes, int n_in,
                              void* d_out, int out_size, void* d_ws, size_t ws_size,
                              hipStream_t stream) {
    const float* x     = (const float*)d_in[0];
    const float* ln1w  = (const float*)d_in[1];
    const float* ln1b  = (const float*)d_in[2];
    const float* ln2w  = (const float*)d_in[3];
    const float* ln2b  = (const float*)d_in[4];
    const float* w_qkv = (const float*)d_in[5];
    const float* b_qkv = (const float*)d_in[6];
    const float* w_out = (const float*)d_in[7];
    const float* b_out = (const float*)d_in[8];
    const float* w_rtr = (const float*)d_in[9];
    const float* wi    = (const float*)d_in[10];
    const float* wo    = (const float*)d_in[11];
    float* out = (float*)d_out;

    char* wsb = (char*)d_ws;
    __hip_bfloat16* wiT  = (__hip_bfloat16*)(wsb + OFF_WIT);
    __hip_bfloat16* woT  = (__hip_bfloat16*)(wsb + OFF_WOT);
    __hip_bfloat16* wqH  = (__hip_bfloat16*)(wsb + OFF_WQH);
    __hip_bfloat16* wqL  = (__hip_bfloat16*)(wsb + OFF_WQL);
    __hip_bfloat16* woH  = (__hip_bfloat16*)(wsb + OFF_WOH);
    __hip_bfloat16* woL  = (__hip_bfloat16*)(wsb + OFF_WOL);
    __hip_bfloat16* h1H  = (__hip_bfloat16*)(wsb + OFF_H1H);
    __hip_bfloat16* h1L  = (__hip_bfloat16*)(wsb + OFF_H1L);
    float*          qkvF = (float*)(wsb + OFF_QKV);
    __hip_bfloat16* hidB = (__hip_bfloat16*)(wsb + OFF_QKV);   // reuse after attn
    float*          h2F  = (float*)(wsb + OFF_H2F);
    __hip_bfloat16* oH   = (__hip_bfloat16*)(wsb + OFF_OH);
    __hip_bfloat16* oL   = (__hip_bfloat16*)(wsb + OFF_OL);
    float*          x2F  = (float*)(wsb + OFF_X2);
    __hip_bfloat16* h2B  = (__hip_bfloat16*)(wsb + OFF_H2B);
    __hip_bfloat16* actB = (__hip_bfloat16*)(wsb + OFF_ACT);
    float* gate = (float*)(wsb + OFF_GATE);
    int* eid    = (int*)(wsb + OFF_EID);
    int* perm   = (int*)(wsb + OFF_PERM);
    int* counts = (int*)(wsb + OFF_CNT);
    int* fill   = (int*)(wsb + OFF_FILL);
    int* ntl    = (int*)(wsb + OFF_NT);
    int* offs   = (int*)(wsb + OFF_OFFS);
    int* te     = (int*)(wsb + OFF_TE);
    int* tsx    = (int*)(wsb + OFF_TS);
    int* trx    = (int*)(wsb + OFF_TR);

    // 0. weight conversion
    k_cvt_split<<<3072, 256, 0, stream>>>(w_qkv, wqH, wqL, 3072 * 1024 / 4);
    k_cvt_split<<<1024, 256, 0, stream>>>(w_out, woH, woL, 1024 * 1024 / 4);
    k_tcvt<<<dim3(4096 / 32, 1024 / 32, EE), 256, 0, stream>>>(wi, wiT, 1024, 4096);
    k_tcvt<<<dim3(1024 / 32, 2048 / 32, EE), 256, 0, stream>>>(wo, woT, 2048, 1024);

    // 1. LN1 + RoPE -> h1 hi/lo
    k_ln<0><<<MM, 256, 0, stream>>>(x, ln1w, ln1b, h1H, h1L, nullptr);
    // 2. qkv = h1 @ w_qkv^T + b_qkv (split precision, f32 out)
    k_mfma_split<0><<<dim3(3072 / 128, MM / 128), 256, 0, stream>>>(
        h1H, h1L, wqH, wqL, b_qkv, nullptr, qkvF, MM, 3072, DD);
    // 3. attention (split-precision MFMA, hi/lo bf16 out)
    k_attn_mfma<<<dim3(SS / QB, HH, BB), 256, 0, stream>>>(qkvF, oH, oL);
    // 4. x2 = x + o @ w_out^T + b_out (split precision, f32)
    k_mfma_split<1><<<dim3(DD / 128, MM / 128), 256, 0, stream>>>(
        oH, oL, woH, woL, b_out, x, x2F, MM, DD, DD);
    // 5. LN2 -> h2 (bf16 + f32)
    k_ln<1><<<MM, 256, 0, stream>>>(x2F, ln2w, ln2b, h2B, nullptr, h2F);
    // 6. zero routing state
    hipMemsetAsync(wsb + OFF_CNT, 0, 68, stream);
    // 7. router (f32 h2 -> exact logits/argmax)
    k_router<<<MM, 64, 0, stream>>>(h2F, w_rtr, out + (size_t)MM * DD, gate, eid, counts);
    // 8-9. tiles + scatter
    k_offsets<<<1, 1, 0, stream>>>(counts, offs, te, tsx, trx, ntl);
    k_scatter<<<MM / 256, 256, 0, stream>>>(eid, offs, fill, perm);
    // 10. hid = h2[perm] @ wiT[e]^T (bf16 out)
    k_mfma<2><<<dim3(FF / 128, MAX_TILES), 256, 0, stream>>>(
        h2B, wiT, nullptr, nullptr, hidB, FF, DD,
        perm, te, tsx, trx, ntl, nullptr);
    // 11. act = silu(a)*g
    k_act<<<MM * 512 / 256, 256, 0, stream>>>(hidB, actB);
    // 12. out = x2 + gate * (act @ woT[e]^T)
    k_mfma<3><<<dim3(DD / 128, MAX_TILES), 256, 0, stream>>>(
        actB, woT, x2F, out, nullptr, DD, FF / 2,
        perm, te, tsx, trx, ntl, gate);
}

// Round 5
// 400.608 us; speedup vs baseline: 4.6008x; 1.0830x over previous
//
#include <hip/hip_runtime.h>
#include <hip/hip_bf16.h>
#include <math.h>

// Problem constants
#define BB 2
#define SS 1024
#define DD 1024
#define FF 4096
#define HH 16
#define EE 8
#define MM (BB*SS)          // 2048 tokens
#define MAX_TILES 24        // sum_e ceil(cnt_e/128) <= 2048/128 + 8

typedef __attribute__((ext_vector_type(8))) short bf16x8;
typedef __attribute__((ext_vector_type(8))) short s16x8;
typedef __attribute__((ext_vector_type(4))) short s16x4;
typedef __attribute__((ext_vector_type(4))) float f32x4;

// ---------------- workspace layout (bytes) ----------------
#define OFF_WIT  ((size_t)0)            // wi^T bf16: 8*4096*1024*2 = 67108864
#define OFF_WOT  ((size_t)67108864)     // wo^T bf16: 33554432
#define OFF_WQH  ((size_t)100663296)    // w_qkv hi bf16: 6291456   (later: K split hi/lo, 8MB)
#define OFF_WQL  ((size_t)106954752)    // w_qkv lo bf16: 6291456
#define OFF_WOH  ((size_t)113246208)    // w_out hi bf16: 2097152
#define OFF_WOL  ((size_t)115343360)    // w_out lo bf16: 2097152
#define OFF_H1H  ((size_t)117440512)    // h1 hi bf16: 4194304      (later: VT hi)
#define OFF_H1L  ((size_t)121634816)    // h1 lo bf16: 4194304      (later: VT lo)
#define OFF_QKV  ((size_t)125829120)    // qkv f32: 25165824; later hid bf16 (16MB)
#define OFF_H2F  ((size_t)142606336)    // h2 f32: 8388608
#define OFF_OH   ((size_t)150994944)    // attn o hi bf16: 4194304
#define OFF_OL   ((size_t)155189248)    // attn o lo bf16: 4194304
#define OFF_X2   ((size_t)159383552)    // x2 f32: 8388608
#define OFF_H2B  ((size_t)167772160)    // h2 bf16: 4194304
#define OFF_ACT  ((size_t)171966464)    // act bf16 (2048+128)*2048*2 = 8912896
#define OFF_GATE ((size_t)180879360)
#define OFF_EID  ((size_t)180887552)
#define OFF_PERM ((size_t)180895744)
#define OFF_CNT  ((size_t)180903936)
#define OFF_FILL ((size_t)180903968)
#define OFF_NT   ((size_t)180904000)
#define OFF_OFFS ((size_t)180904064)
#define OFF_TE   ((size_t)180904192)
#define OFF_TS   ((size_t)180904320)
#define OFF_TR   ((size_t)180904448)
// attention K/V split buffers (reuse dead regions)
#define OFF_KSH  OFF_WQH                         // 4MB
#define OFF_KSL  (OFF_WQH + 4194304)             // 4MB (spills into wqL region - dead)
#define OFF_VTH  OFF_H1H                         // 4MB
#define OFF_VTL  OFF_H1L                         // 4MB

// ---------------- async global->LDS (16B per lane) ----------------
__device__ __forceinline__ void gload16(const void* g, void* l) {
    __builtin_amdgcn_global_load_lds(
        (const __attribute__((address_space(1))) unsigned int*)g,
        (__attribute__((address_space(3))) unsigned int*)l, 16, 0, 0);
}

__device__ __forceinline__ short bfh(float v) {
    __hip_bfloat16 h = __float2bfloat16(v);
    return *(short*)&h;
}
__device__ __forceinline__ float bf2f(short s) {
    __hip_bfloat16 h = *(__hip_bfloat16*)&s;
    return __bfloat162float(h);
}

__device__ __forceinline__ void split_write(float v, __hip_bfloat16* hp, __hip_bfloat16* lp, size_t idx) {
    __hip_bfloat16 h = __float2bfloat16(v);
    hp[idx] = h;
    lp[idx] = __float2bfloat16(v - __bfloat162float(h));
}

// ---------------- f32 -> bf16 hi/lo split convert ----------------
__global__ void k_cvt_split(const float* __restrict__ in, __hip_bfloat16* __restrict__ hi,
                            __hip_bfloat16* __restrict__ lo, int n4) {
    int i = blockIdx.x * 256 + threadIdx.x;
    if (i >= n4) return;
    float4 v = ((const float4*)in)[i];
    split_write(v.x, hi, lo, (size_t)i * 4 + 0);
    split_write(v.y, hi, lo, (size_t)i * 4 + 1);
    split_write(v.z, hi, lo, (size_t)i * 4 + 2);
    split_write(v.w, hi, lo, (size_t)i * 4 + 3);
}

// ---------------- batched transpose-convert: in (R,C) f32 -> out (C,R) bf16 ----------------
__global__ void k_tcvt(const float* __restrict__ in, __hip_bfloat16* __restrict__ out, int R, int C) {
    __shared__ float tile[32][33];
    int c0 = blockIdx.x * 32, r0 = blockIdx.y * 32;
    size_t eoff = (size_t)blockIdx.z * R * C;
    in += eoff; out += eoff;
    int t = threadIdx.x;
    int i = t >> 3, j0 = (t & 7) * 4;
    float4 v = *(const float4*)&in[(size_t)(r0 + i) * C + c0 + j0];
    tile[i][j0 + 0] = v.x; tile[i][j0 + 1] = v.y; tile[i][j0 + 2] = v.z; tile[i][j0 + 3] = v.w;
    __syncthreads();
#pragma unroll
    for (int q = 0; q < 4; ++q)
        out[(size_t)(c0 + i) * R + r0 + j0 + q] = __float2bfloat16(tile[j0 + q][i]);
}

// ---------------- LayerNorm: MODE 0 = +RoPE, hi/lo out; MODE 1 = plain, bf16+f32 out ----------------
template<int MODE>
__global__ void k_ln(const float* __restrict__ x, const float* __restrict__ w,
                     const float* __restrict__ b, __hip_bfloat16* __restrict__ hi,
                     __hip_bfloat16* __restrict__ lo, float* __restrict__ f32o) {
    int m = blockIdx.x;
    int s = m & (SS - 1);
    __shared__ float row[DD];
    __shared__ float red[8];
    int t = threadIdx.x;
    const float* xp = x + (size_t)m * DD;
    float sum = 0.f, sumsq = 0.f;
#pragma unroll
    for (int l = 0; l < 4; ++l) {
        int i = t + l * 256;
        float v = xp[i];
        row[i] = v;
        sum += v; sumsq += v * v;
    }
#pragma unroll
    for (int off = 32; off; off >>= 1) {
        sum   += __shfl_xor(sum, off);
        sumsq += __shfl_xor(sumsq, off);
    }
    int wid = t >> 6, lane = t & 63;
    if (lane == 0) { red[wid] = sum; red[4 + wid] = sumsq; }
    __syncthreads();
    sum   = red[0] + red[1] + red[2] + red[3];
    sumsq = red[4] + red[5] + red[6] + red[7];
    float mean = sum * (1.f / DD);
    float var  = sumsq * (1.f / DD) - mean * mean;
    float rstd = rsqrtf(var + 1e-5f);
    size_t base = (size_t)m * DD;
    if (MODE == 0) {
        const float kln = logf(10000.f) / 512.f;
#pragma unroll
        for (int l = 0; l < 2; ++l) {
            int i = t + l * 256;   // 0..511
            float n1 = (row[i]       - mean) * rstd * w[i]       + b[i];
            float n2 = (row[i + 512] - mean) * rstd * w[i + 512] + b[i + 512];
            float inv = expf(-(float)i * kln);
            float ang = (float)s * inv;
            float c = cosf(ang), sn = sinf(ang);
            split_write(n1 * c - n2 * sn,  hi, lo, base + i);
            split_write(n1 * sn + n2 * c, hi, lo, base + i + 512);
        }
    } else {
#pragma unroll
        for (int l = 0; l < 4; ++l) {
            int i = t + l * 256;
            float v = (row[i] - mean) * rstd * w[i] + b[i];
            hi[base + i] = __float2bfloat16(v);
            f32o[base + i] = v;
        }
    }
}

// ---------------- split-precision MFMA GEMM: C = A @ Bt^T + bias (+addsrc) ----------------
template<int MODE>
__global__ void k_mfma_split(const __hip_bfloat16* __restrict__ Ah, const __hip_bfloat16* __restrict__ Al,
                             const __hip_bfloat16* __restrict__ Bh, const __hip_bfloat16* __restrict__ Bl,
                             const float* __restrict__ bias, const float* __restrict__ addsrc,
                             float* __restrict__ Cf, int M, int N, int K) {
    __shared__ __align__(16) short AsH[128 * 32];
    __shared__ __align__(16) short AsL[128 * 32];
    __shared__ __align__(16) short BsH[128 * 32];
    __shared__ __align__(16) short BsL[128 * 32];
    int m0 = blockIdx.y * 128, n0 = blockIdx.x * 128;
    const int t = threadIdx.x;
    const int w = t >> 6, lane = t & 63;
    const int wr = w >> 1, wc = w & 1;
    const int sid = w * 64 + lane;

    f32x4 acc[4][4] = {};

    for (int k0 = 0; k0 < K; k0 += 32) {
#pragma unroll
        for (int j = 0; j < 2; ++j) {
            int id = j * 256 + sid;
            int rrow = id >> 2, sl = id & 3;
            int slog = sl ^ ((rrow >> 1) & 3);
            size_t lbase = (size_t)(j * 256 + w * 64) * 8;
            size_t gaoff = (size_t)(m0 + rrow) * K + k0 + slog * 8;
            gload16(Ah + gaoff, &AsH[lbase]);
            gload16(Al + gaoff, &AsL[lbase]);
            size_t gboff = (size_t)(n0 + rrow) * K + k0 + slog * 8;
            gload16(Bh + gboff, &BsH[lbase]);
            gload16(Bl + gboff, &BsL[lbase]);
        }
        __syncthreads();
        bf16x8 ah[4], al[4], bh[4], bl[4];
#pragma unroll
        for (int i = 0; i < 4; ++i) {
            int ra = wr * 64 + i * 16 + (lane & 15);
            int pa = (lane >> 4) ^ ((ra >> 1) & 3);
            ah[i] = *(const bf16x8*)&AsH[ra * 32 + pa * 8];
            al[i] = *(const bf16x8*)&AsL[ra * 32 + pa * 8];
            int rb = wc * 64 + i * 16 + (lane & 15);
            int pb = (lane >> 4) ^ ((rb >> 1) & 3);
            bh[i] = *(const bf16x8*)&BsH[rb * 32 + pb * 8];
            bl[i] = *(const bf16x8*)&BsL[rb * 32 + pb * 8];
        }
#pragma unroll
        for (int i = 0; i < 4; ++i)
#pragma unroll
            for (int n = 0; n < 4; ++n) {
                acc[i][n] = __builtin_amdgcn_mfma_f32_16x16x32_bf16(ah[i], bh[n], acc[i][n], 0, 0, 0);
                acc[i][n] = __builtin_amdgcn_mfma_f32_16x16x32_bf16(ah[i], bl[n], acc[i][n], 0, 0, 0);
                acc[i][n] = __builtin_amdgcn_mfma_f32_16x16x32_bf16(al[i], bh[n], acc[i][n], 0, 0, 0);
            }
        __syncthreads();
    }

    int cn = n0 + wc * 64 + (lane & 15);
#pragma unroll
    for (int i = 0; i < 4; ++i) {
#pragma unroll
        for (int n = 0; n < 4; ++n) {
            int col = cn + n * 16;
#pragma unroll
            for (int q = 0; q < 4; ++q) {
                int r = wr * 64 + i * 16 + (lane >> 4) * 4 + q;
                float v = acc[i][n][q] + bias[col];
                if (MODE == 1) v += addsrc[(size_t)(m0 + r) * N + col];
                Cf[(size_t)(m0 + r) * N + col] = v;
            }
        }
    }
}

// ---------------- plain bf16 MFMA GEMM for MoE ----------------
template<int MODE>
__global__ void k_mfma(const __hip_bfloat16* __restrict__ A,
                       const __hip_bfloat16* __restrict__ Bt,
                       const float* __restrict__ addsrc,
                       float* __restrict__ Cf,
                       __hip_bfloat16* __restrict__ Cb,
                       int N, int K,
                       const int* __restrict__ perm,
                       const int* __restrict__ te, const int* __restrict__ ts,
                       const int* __restrict__ tr, const int* __restrict__ ntl,
                       const float* __restrict__ gate) {
    __shared__ __align__(16) short As[128 * 32];
    __shared__ __align__(16) short Bs[128 * 32];
    __shared__ int permS[128];
    int tile = blockIdx.y;
    if (tile >= *ntl) return;
    int e = te[tile], rs = ts[tile], rows = tr[tile];
    if (threadIdx.x < 128) {
        int r = threadIdx.x;
        permS[r] = (r < rows) ? perm[rs + r] : 0;
    }
    __syncthreads();
    int n0 = blockIdx.x * 128;
    const int t = threadIdx.x;
    const int w = t >> 6, lane = t & 63;
    const int wr = w >> 1, wc = w & 1;
    const int sid = w * 64 + lane;

    const __hip_bfloat16* Bp = Bt + (size_t)e * (size_t)N * (size_t)K;

    f32x4 acc[4][4] = {};

    for (int k0 = 0; k0 < K; k0 += 32) {
#pragma unroll
        for (int j = 0; j < 2; ++j) {
            int id = j * 256 + sid;
            int rrow = id >> 2, sl = id & 3;
            int slog = sl ^ ((rrow >> 1) & 3);
            const __hip_bfloat16* ga;
            if (MODE == 2) ga = A + (size_t)permS[rrow] * K + k0 + slog * 8;
            else           ga = A + (size_t)(rs + rrow) * K + k0 + slog * 8;
            size_t lbase = (size_t)(j * 256 + w * 64) * 8;
            gload16(ga, &As[lbase]);
            gload16(Bp + (size_t)(n0 + rrow) * K + k0 + slog * 8, &Bs[lbase]);
        }
        __syncthreads();
        bf16x8 af[4], bfr[4];
#pragma unroll
        for (int i = 0; i < 4; ++i) {
            int ra = wr * 64 + i * 16 + (lane & 15);
            int pa = (lane >> 4) ^ ((ra >> 1) & 3);
            af[i] = *(const bf16x8*)&As[ra * 32 + pa * 8];
            int rb = wc * 64 + i * 16 + (lane & 15);
            int pb = (lane >> 4) ^ ((rb >> 1) & 3);
            bfr[i] = *(const bf16x8*)&Bs[rb * 32 + pb * 8];
        }
#pragma unroll
        for (int i = 0; i < 4; ++i)
#pragma unroll
            for (int n = 0; n < 4; ++n)
                acc[i][n] = __builtin_amdgcn_mfma_f32_16x16x32_bf16(af[i], bfr[n], acc[i][n], 0, 0, 0);
        __syncthreads();
    }

    int cn = n0 + wc * 64 + (lane & 15);
#pragma unroll
    for (int i = 0; i < 4; ++i) {
#pragma unroll
        for (int n = 0; n < 4; ++n) {
            int col = cn + n * 16;
#pragma unroll
            for (int q = 0; q < 4; ++q) {
                int r = wr * 64 + i * 16 + (lane >> 4) * 4 + q;
                if (r >= rows) continue;
                float v = acc[i][n][q];
                if (MODE == 2) {
                    Cb[(size_t)(rs + r) * N + col] = __float2bfloat16(v);
                } else {
                    int tok = permS[r];
                    Cf[(size_t)tok * N + col] = addsrc[(size_t)tok * N + col] + gate[tok] * v;
                }
            }
        }
    }
}

// ---------------- attention prep: split K -> [b,h,s,d] swz, V^T -> [b,h,d,s] swz ----------------
// 16B-slot swizzle baked into GLOBAL layout: phys_slot = logical_slot ^ (row&7)
// (row = s for K, row = d for V^T), so global_load_lds copies linearly and
// ds_read_b128 fragment reads are conflict-free (G4 / m214 pattern).
__global__ void k_prep(const float* __restrict__ qkv, short* __restrict__ KH, short* __restrict__ KL,
                       short* __restrict__ VH, short* __restrict__ VL) {
    __shared__ float tile[64][65];
    int b = blockIdx.z, h = blockIdx.y, s0 = blockIdx.x * 64;
    int t = threadIdx.x;
    int row = t >> 2, c0 = (t & 3) * 16;
    const float* kp = qkv + (size_t)(b * SS + s0 + row) * 3072 + 1024 + h * 64 + c0;
    const float* vp = kp + 1024;
    // K: split + slot-swizzled write
    {
        size_t krow = ((size_t)(b * HH + h) * SS + s0 + row) * 64;
        int key = (s0 + row) & 7;
#pragma unroll
        for (int g2 = 0; g2 < 2; ++g2) {
            s16x8 hv, lv;
#pragma unroll
            for (int j = 0; j < 8; ++j) {
                float v = kp[g2 * 8 + j];
                short hh = bfh(v);
                hv[j] = hh; lv[j] = bfh(v - bf2f(hh));
            }
            int p = ((c0 >> 3) + g2) ^ key;
            *(s16x8*)&KH[krow + p * 8] = hv;
            *(s16x8*)&KL[krow + p * 8] = lv;
        }
    }
    // V: stage f32, transpose, split + slot-swizzled write
#pragma unroll
    for (int j = 0; j < 16; ++j) tile[row][c0 + j] = vp[j];
    __syncthreads();
    {
        int d = t >> 2, sc = (t & 3) * 16;
        size_t vrow = ((size_t)(b * HH + h) * 64 + d) * SS + s0;
        int key = d & 7;
#pragma unroll
        for (int g2 = 0; g2 < 2; ++g2) {
            s16x8 hv, lv;
#pragma unroll
            for (int j = 0; j < 8; ++j) {
                float v = tile[sc + g2 * 8 + j][d];
                short hh = bfh(v);
                hv[j] = hh; lv[j] = bfh(v - bf2f(hh));
            }
            int p = ((sc >> 3) + g2) ^ key;
            *(s16x8*)&VH[vrow + p * 8] = hv;
            *(s16x8*)&VL[vrow + p * 8] = lv;
        }
    }
}

// ---------------- MFMA flash attention, split precision, 8 waves x 16 q-rows ----------------
#define LDP 72
__global__ __launch_bounds__(512, 1)
void k_attn_mfma(const float* __restrict__ qkv,
                 const short* __restrict__ KH, const short* __restrict__ KL,
                 const short* __restrict__ VH, const short* __restrict__ VL,
                 __hip_bfloat16* __restrict__ ohi, __hip_bfloat16* __restrict__ olo) {
    __shared__ __align__(16) short Ks[64 * 64], Kl2[64 * 64], Vs[64 * 64], Vl2[64 * 64];
    __shared__ __align__(16) short PhS[8][16 * LDP], PlS[8][16 * LDP];
    int b = blockIdx.z, h = blockIdx.y, q0 = blockIdx.x * 128;
    int t = threadIdx.x;
    int w = t >> 6, lane = t & 63;
    int g = lane >> 4, r16 = lane & 15;
    int srow = t >> 3, sslot = t & 7;

    // ---- Q fragments direct from f32 qkv, prescale 1/8, split in-reg
    bf16x8 qfh[2], qfl[2];
    {
        const float* qp = qkv + (size_t)(b * SS + q0 + w * 16 + r16) * 3072 + h * 64;
#pragma unroll
        for (int ks = 0; ks < 2; ++ks) {
            float vv[8];
            *(float4*)&vv[0] = *(const float4*)(qp + ks * 32 + g * 8);
            *(float4*)&vv[4] = *(const float4*)(qp + ks * 32 + g * 8 + 4);
#pragma unroll
            for (int j = 0; j < 8; ++j) {
                float sv = vv[j] * 0.125f;
                short hh = bfh(sv);
                qfh[ks][j] = hh;
                qfl[ks][j] = bfh(sv - bf2f(hh));
            }
        }
    }

    const size_t kbase = ((size_t)(b * HH + h) * SS) * 64;
    const size_t vbase = ((size_t)(b * HH + h) * 64) * SS;

    float mrun[4], lrun[4];
    f32x4 oacc[4] = {};
#pragma unroll
    for (int q = 0; q < 4; ++q) { mrun[q] = -1e30f; lrun[q] = 0.f; }

    for (int k0 = 0; k0 < SS; k0 += 64) {
        // ---- stage K/V split tiles (linear copy; swizzle already in global layout)
        gload16(KH + kbase + (size_t)(k0 + srow) * 64 + sslot * 8, Ks  + w * 512);
        gload16(KL + kbase + (size_t)(k0 + srow) * 64 + sslot * 8, Kl2 + w * 512);
        gload16(VH + vbase + (size_t)srow * SS + k0 + sslot * 8,   Vs  + w * 512);
        gload16(VL + vbase + (size_t)srow * SS + k0 + sslot * 8,   Vl2 + w * 512);
        __syncthreads();

        // ---- S = Q K^T (split, 3 MFMA per fragment)
        f32x4 accs[4] = {};
#pragma unroll
        for (int ks = 0; ks < 2; ++ks) {
            bf16x8 kfh[4], kfl[4];
#pragma unroll
            for (int n = 0; n < 4; ++n) {
                int rb = n * 16 + r16;
                int p = (ks * 4 + g) ^ (r16 & 7);
                kfh[n] = *(const bf16x8*)&Ks[rb * 64 + p * 8];
                kfl[n] = *(const bf16x8*)&Kl2[rb * 64 + p * 8];
            }
#pragma unroll
            for (int n = 0; n < 4; ++n) {
                accs[n] = __builtin_amdgcn_mfma_f32_16x16x32_bf16(qfh[ks], kfh[n], accs[n], 0, 0, 0);
                accs[n] = __builtin_amdgcn_mfma_f32_16x16x32_bf16(qfh[ks], kfl[n], accs[n], 0, 0, 0);
                accs[n] = __builtin_amdgcn_mfma_f32_16x16x32_bf16(qfl[ks], kfh[n], accs[n], 0, 0, 0);
            }
        }

        // ---- online softmax
        float mn[4], corr[4], psum[4];
#pragma unroll
        for (int q = 0; q < 4; ++q) {
            float m = fmaxf(fmaxf(accs[0][q], accs[1][q]), fmaxf(accs[2][q], accs[3][q]));
            m = fmaxf(m, __shfl_xor(m, 1));
            m = fmaxf(m, __shfl_xor(m, 2));
            m = fmaxf(m, __shfl_xor(m, 4));
            m = fmaxf(m, __shfl_xor(m, 8));
            mn[q] = fmaxf(mrun[q], m);
            corr[q] = expf(mrun[q] - mn[q]);
            mrun[q] = mn[q];
            psum[q] = 0.f;
        }
#pragma unroll
        for (int n = 0; n < 4; ++n)
#pragma unroll
            for (int q = 0; q < 4; ++q) {
                float p = expf(accs[n][q] - mn[q]);
                psum[q] += p;
                short ph = bfh(p);
                PhS[w][(g * 4 + q) * LDP + n * 16 + r16] = ph;
                PlS[w][(g * 4 + q) * LDP + n * 16 + r16] = bfh(p - bf2f(ph));
            }
#pragma unroll
        for (int q = 0; q < 4; ++q) {
            psum[q] += __shfl_xor(psum[q], 1);
            psum[q] += __shfl_xor(psum[q], 2);
            psum[q] += __shfl_xor(psum[q], 4);
            psum[q] += __shfl_xor(psum[q], 8);
            lrun[q] = lrun[q] * corr[q] + psum[q];
#pragma unroll
            for (int n = 0; n < 4; ++n) oacc[n][q] *= corr[q];
        }

        // ---- O += P V (split)
#pragma unroll
        for (int ks = 0; ks < 2; ++ks) {
            bf16x8 vfh[4], vfl[4];
#pragma unroll
            for (int n = 0; n < 4; ++n) {
                int rb = n * 16 + r16;
                int p = (ks * 4 + g) ^ (r16 & 7);
                vfh[n] = *(const bf16x8*)&Vs[rb * 64 + p * 8];
                vfl[n] = *(const bf16x8*)&Vl2[rb * 64 + p * 8];
            }
            bf16x8 pfh = *(const bf16x8*)&PhS[w][r16 * LDP + ks * 32 + g * 8];
            bf16x8 pfl = *(const bf16x8*)&PlS[w][r16 * LDP + ks * 32 + g * 8];
#pragma unroll
            for (int n = 0; n < 4; ++n) {
                oacc[n] = __builtin_amdgcn_mfma_f32_16x16x32_bf16(pfh, vfh[n], oacc[n], 0, 0, 0);
                oacc[n] = __builtin_amdgcn_mfma_f32_16x16x32_bf16(pfh, vfl[n], oacc[n], 0, 0, 0);
                oacc[n] = __builtin_amdgcn_mfma_f32_16x16x32_bf16(pfl, vfh[n], oacc[n], 0, 0, 0);
            }
        }
        __syncthreads();
    }

    // ---- epilogue
    float invl[4];
#pragma unroll
    for (int q = 0; q < 4; ++q) invl[q] = 1.f / lrun[q];
#pragma unroll
    for (int n = 0; n < 4; ++n) {
        int col = h * 64 + n * 16 + r16;
#pragma unroll
        for (int q = 0; q < 4; ++q) {
            int rowg = b * SS + q0 + w * 16 + g * 4 + q;
            split_write(oacc[n][q] * invl[q], ohi, olo, (size_t)rowg * DD + col);
        }
    }
}

// ---------------- router (f32 h2 in) ----------------
__global__ void k_router(const float* __restrict__ h2, const float* __restrict__ wr,
                         float* __restrict__ logits_out, float* __restrict__ gate,
                         int* __restrict__ eid, int* __restrict__ counts) {
    int m = blockIdx.x;
    int lane = threadIdx.x;   // 64 threads
    const float* hp = h2 + (size_t)m * DD;
    float acc[EE] = {};
    for (int k = lane; k < DD; k += 64) {
        float v = hp[k];
        const float* wp = wr + (size_t)k * EE;
#pragma unroll
        for (int n = 0; n < EE; ++n) acc[n] += v * wp[n];
    }
#pragma unroll
    for (int off = 32; off; off >>= 1)
#pragma unroll
        for (int n = 0; n < EE; ++n) acc[n] += __shfl_xor(acc[n], off);
    if (lane == 0) {
        float mx = acc[0]; int best = 0;
#pragma unroll
        for (int n = 1; n < EE; ++n) if (acc[n] > mx) { mx = acc[n]; best = n; }
        float den = 0.f;
#pragma unroll
        for (int n = 0; n < EE; ++n) den += expf(acc[n] - mx);
        gate[m] = 1.f / den;
        eid[m] = best;
        atomicAdd(&counts[best], 1);
#pragma unroll
        for (int n = 0; n < EE; ++n) logits_out[(size_t)m * EE + n] = acc[n];
    }
}

// ---------------- routing bookkeeping (BM=128 tiles) ----------------
__global__ void k_offsets(const int* __restrict__ counts, int* __restrict__ offs,
                          int* __restrict__ te, int* __restrict__ ts, int* __restrict__ tr,
                          int* __restrict__ ntiles) {
    if (threadIdx.x != 0 || blockIdx.x != 0) return;
    int off = 0, nt = 0;
    for (int e = 0; e < EE; ++e) {
        offs[e] = off;
        int c = counts[e];
        for (int t0 = 0; t0 < c; t0 += 128) {
            te[nt] = e; ts[nt] = off + t0; tr[nt] = (c - t0 < 128) ? (c - t0) : 128; ++nt;
        }
        off += c;
    }
    offs[EE] = off;
    *ntiles = nt;
}

__global__ void k_scatter(const int* __restrict__ eid, const int* __restrict__ offs,
                          int* __restrict__ fill, int* __restrict__ perm) {
    int tok = blockIdx.x * 256 + threadIdx.x;
    if (tok >= MM) return;
    int e = eid[tok];
    int pos = offs[e] + atomicAdd(&fill[e], 1);
    perm[pos] = tok;
}

// ---------------- silu(a)*g: hid (p,4096) bf16 -> act (p,2048) bf16 ----------------
__global__ void k_act(const __hip_bfloat16* __restrict__ hid, __hip_bfloat16* __restrict__ act) {
    int idx = blockIdx.x * 256 + threadIdx.x;
    int p = idx >> 9, c4 = (idx & 511) * 4;
    const __hip_bfloat16* ap = hid + (size_t)p * FF + c4;
    const __hip_bfloat16* gp = ap + 2048;
    __hip_bfloat16* op = act + (size_t)p * 2048 + c4;
#pragma unroll
    for (int q = 0; q < 4; ++q) {
        float a = __bfloat162float(ap[q]);
        float g = __bfloat162float(gp[q]);
        op[q] = __float2bfloat16((a / (1.f + expf(-a))) * g);
    }
}

// ---------------- launch ----------------
extern "C" void kernel_launch(void* const* d_in, const int* in_sizes, int n_in,
                              void* d_out, int out_size, void* d_ws, size_t ws_size,
                              hipStream_t stream) {
    const float* x     = (const float*)d_in[0];
    const float* ln1w  = (const float*)d_in[1];
    const float* ln1b  = (const float*)d_in[2];
    const float* ln2w  = (const float*)d_in[3];
    const float* ln2b  = (const float*)d_in[4];
    const float* w_qkv = (const float*)d_in[5];
    const float* b_qkv = (const float*)d_in[6];
    const float* w_out = (const float*)d_in[7];
    const float* b_out = (const float*)d_in[8];
    const float* w_rtr = (const float*)d_in[9];
    const float* wi    = (const float*)d_in[10];
    const float* wo    = (const float*)d_in[11];
    float* out = (float*)d_out;

    char* wsb = (char*)d_ws;
    __hip_bfloat16* wiT  = (__hip_bfloat16*)(wsb + OFF_WIT);
    __hip_bfloat16* woT  = (__hip_bfloat16*)(wsb + OFF_WOT);
    __hip_bfloat16* wqH  = (__hip_bfloat16*)(wsb + OFF_WQH);
    __hip_bfloat16* wqL  = (__hip_bfloat16*)(wsb + OFF_WQL);
    __hip_bfloat16* woH  = (__hip_bfloat16*)(wsb + OFF_WOH);
    __hip_bfloat16* woL  = (__hip_bfloat16*)(wsb + OFF_WOL);
    __hip_bfloat16* h1H  = (__hip_bfloat16*)(wsb + OFF_H1H);
    __hip_bfloat16* h1L  = (__hip_bfloat16*)(wsb + OFF_H1L);
    float*          qkvF = (float*)(wsb + OFF_QKV);
    __hip_bfloat16* hidB = (__hip_bfloat16*)(wsb + OFF_QKV);   // reuse after attn
    float*          h2F  = (float*)(wsb + OFF_H2F);
    __hip_bfloat16* oH   = (__hip_bfloat16*)(wsb + OFF_OH);
    __hip_bfloat16* oL   = (__hip_bfloat16*)(wsb + OFF_OL);
    float*          x2F  = (float*)(wsb + OFF_X2);
    __hip_bfloat16* h2B  = (__hip_bfloat16*)(wsb + OFF_H2B);
    __hip_bfloat16* actB = (__hip_bfloat16*)(wsb + OFF_ACT);
    short* KSH = (short*)(wsb + OFF_KSH);
    short* KSL = (short*)(wsb + OFF_KSL);
    short* VTH = (short*)(wsb + OFF_VTH);
    short* VTL = (short*)(wsb + OFF_VTL);
    float* gate = (float*)(wsb + OFF_GATE);
    int* eid    = (int*)(wsb + OFF_EID);
    int* perm   = (int*)(wsb + OFF_PERM);
    int* counts = (int*)(wsb + OFF_CNT);
    int* fill   = (int*)(wsb + OFF_FILL);
    int* ntl    = (int*)(wsb + OFF_NT);
    int* offs   = (int*)(wsb + OFF_OFFS);
    int* te     = (int*)(wsb + OFF_TE);
    int* tsx    = (int*)(wsb + OFF_TS);
    int* trx    = (int*)(wsb + OFF_TR);

    // 0. weight conversion
    k_cvt_split<<<3072, 256, 0, stream>>>(w_qkv, wqH, wqL, 3072 * 1024 / 4);
    k_cvt_split<<<1024, 256, 0, stream>>>(w_out, woH, woL, 1024 * 1024 / 4);
    k_tcvt<<<dim3(4096 / 32, 1024 / 32, EE), 256, 0, stream>>>(wi, wiT, 1024, 4096);
    k_tcvt<<<dim3(1024 / 32, 2048 / 32, EE), 256, 0, stream>>>(wo, woT, 2048, 1024);

    // 1. LN1 + RoPE -> h1 hi/lo
    k_ln<0><<<MM, 256, 0, stream>>>(x, ln1w, ln1b, h1H, h1L, nullptr);
    // 2. qkv = h1 @ w_qkv^T + b_qkv (split precision, f32 out)
    k_mfma_split<0><<<dim3(3072 / 128, MM / 128), 256, 0, stream>>>(
        h1H, h1L, wqH, wqL, b_qkv, nullptr, qkvF, MM, 3072, DD);
    // 2.5 prep: split K + transposed V (overwrites dead wq/h1 regions)
    k_prep<<<dim3(SS / 64, HH, BB), 256, 0, stream>>>(qkvF, KSH, KSL, VTH, VTL);
    // 3. attention (split-precision MFMA, hi/lo bf16 out)
    k_attn_mfma<<<dim3(SS / 128, HH, BB), 512, 0, stream>>>(qkvF, KSH, KSL, VTH, VTL, oH, oL);
    // 4. x2 = x + o @ w_out^T + b_out (split precision, f32)
    k_mfma_split<1><<<dim3(DD / 128, MM / 128), 256, 0, stream>>>(
        oH, oL, woH, woL, b_out, x, x2F, MM, DD, DD);
    // 5. LN2 -> h2 (bf16 + f32)
    k_ln<1><<<MM, 256, 0, stream>>>(x2F, ln2w, ln2b, h2B, nullptr, h2F);
    // 6. zero routing state
    hipMemsetAsync(wsb + OFF_CNT, 0, 68, stream);
    // 7. router (f32 h2 -> exact logits/argmax)
    k_router<<<MM, 64, 0, stream>>>(h2F, w_rtr, out + (size_t)MM * DD, gate, eid, counts);
    // 8-9. tiles + scatter
    k_offsets<<<1, 1, 0, stream>>>(counts, offs, te, tsx, trx, ntl);
    k_scatter<<<MM / 256, 256, 0, stream>>>(eid, offs, fill, perm);
    // 10. hid = h2[perm] @ wiT[e]^T (bf16 out)
    k_mfma<2><<<dim3(FF / 128, MAX_TILES), 256, 0, stream>>>(
        h2B, wiT, nullptr, nullptr, hidB, FF, DD,
        perm, te, tsx, trx, ntl, nullptr);
    // 11. act = silu(a)*g
    k_act<<<MM * 512 / 256, 256, 0, stream>>>(hidB, actB);
    // 12. out = x2 + gate * (act @ woT[e]^T)
    k_mfma<3><<<dim3(DD / 128, MAX_TILES), 256, 0, stream>>>(
        actB, woT, x2F, out, nullptr, DD, FF / 2,
        perm, te, tsx, trx, ntl, gate);
}